// Round 4
// baseline (7409.489 us; speedup 1.0000x reference)
//
#include <hip/hip_runtime.h>
#include <hip/hip_bf16.h>
#include <stdint.h>
#include <stddef.h>

typedef __hip_bfloat16 bf16;
typedef __attribute__((ext_vector_type(8))) short bfrag;
typedef __attribute__((ext_vector_type(4))) float ffrag;

#define HDIM 1024
#define BATCH 64
#define TSTEPS 256
#define GDIM 4096
#define VOCAB 32000
#define NWG_SEQ 256   // 256 WGs x 512 threads; WG owns 4 hidden cols (16 gate cols)

__device__ __forceinline__ float b2f(bf16 x) { return __bfloat162float(x); }
__device__ __forceinline__ bf16 f2b(float x) { return __float2bfloat16(x); }
__device__ __forceinline__ short f2bs(float x) {
  bf16 b = __float2bfloat16(x);
  return *reinterpret_cast<short*>(&b);
}
__device__ __forceinline__ float bs2f(unsigned short u) {
  union { unsigned int i; float f; } v;
  v.i = ((unsigned int)u) << 16;
  return v.f;
}
__device__ __forceinline__ ffrag mfma16(bfrag a, bfrag b, ffrag c) {
  return __builtin_amdgcn_mfma_f32_16x16x32_bf16(a, b, c, 0, 0, 0);
}
__device__ __forceinline__ float sigm(float x) { return 1.0f / (1.0f + __expf(-x)); }
__device__ __forceinline__ float tanhfast(float x) {
  float e = __expf(2.0f * x);
  return 1.0f - 2.0f / (e + 1.0f);
}

// agent-scope point-coherent ops (bypass non-coherent L1/L2; no cache-wide fences)
__device__ __forceinline__ void store_u64_agent(unsigned long long* p, unsigned long long v) {
  __hip_atomic_store(p, v, __ATOMIC_RELAXED, __HIP_MEMORY_SCOPE_AGENT);
}
__device__ __forceinline__ unsigned long long load_u64_agent(const unsigned long long* p) {
  return __hip_atomic_load(p, __ATOMIC_RELAXED, __HIP_MEMORY_SCOPE_AGENT);
}
__device__ __forceinline__ void store_u32_agent(unsigned* p, unsigned v) {
  __hip_atomic_store(p, v, __ATOMIC_RELAXED, __HIP_MEMORY_SCOPE_AGENT);
}

// ---------------- convert f32 -> bf16 ----------------
__global__ void convert_bf16_kernel(const float* __restrict__ src, bf16* __restrict__ dst, int n4) {
  int i = blockIdx.x * 256 + threadIdx.x;
  if (i >= n4) return;
  float4 v = reinterpret_cast<const float4*>(src)[i];
  ushort4 o;
  o.x = (unsigned short)f2bs(v.x);
  o.y = (unsigned short)f2bs(v.y);
  o.z = (unsigned short)f2bs(v.z);
  o.w = (unsigned short)f2bs(v.w);
  reinterpret_cast<ushort4*>(dst)[i] = o;
}

// ---------------- embedding gather -> bf16 ----------------
__global__ void embed_kernel(const int* __restrict__ ids, const float* __restrict__ table,
                             bf16* __restrict__ x, int n4) {
  int i = blockIdx.x * 256 + threadIdx.x;
  if (i >= n4) return;
  int row = i >> 8;   // H/4 = 256 float4 per (b,t) row
  int c4 = i & 255;
  int tok = ids[row];
  float4 v = reinterpret_cast<const float4*>(table)[(size_t)tok * 256 + c4];
  ushort4 o;
  o.x = (unsigned short)f2bs(v.x);
  o.y = (unsigned short)f2bs(v.y);
  o.z = (unsigned short)f2bs(v.z);
  o.w = (unsigned short)f2bs(v.w);
  reinterpret_cast<ushort4*>(x)[i] = o;
}

// ---------------- xg = x @ W_ih^T + b_ih + b_hh ----------------
// A: (16384,1024) bf16 K-major; W: (4096,1024) bf16 K-major.
// out xg layout: (wg, t, b, 16) -- per-recurrence-WG contiguous.
#define BMX 128
#define BNX 128
#define BKX 64

__launch_bounds__(256, 2)
__global__ void gemm_xg_kernel(const bf16* __restrict__ A,
                               const bf16* __restrict__ W,
                               const float* __restrict__ bih,
                               const float* __restrict__ bhh,
                               bf16* __restrict__ xg) {
  __shared__ bf16 As[BMX][BKX + 8];
  __shared__ bf16 Bs[BNX][BKX + 8];
  const int n0 = blockIdx.x * BNX;
  const int m0 = blockIdx.y * BMX;
  const int tid = threadIdx.x;
  const int w = tid >> 6, l = tid & 63;
  const int wm = (w >> 1) * 64, wn = (w & 1) * 64;
  const int lr = l & 15, lk = (l >> 4) * 8;

  ffrag acc[4][4];
#pragma unroll
  for (int i = 0; i < 4; ++i)
#pragma unroll
    for (int j = 0; j < 4; ++j) acc[i][j] = ffrag{0.f, 0.f, 0.f, 0.f};

  const int sr = tid >> 1, sh = (tid & 1) * 32;
  for (int kb = 0; kb < HDIM; kb += BKX) {
    __syncthreads();
    {
      const uint4* ga = reinterpret_cast<const uint4*>(&A[(size_t)(m0 + sr) * HDIM + kb + sh]);
      uint4* la = reinterpret_cast<uint4*>(&As[sr][sh]);
      la[0] = ga[0]; la[1] = ga[1]; la[2] = ga[2]; la[3] = ga[3];
      const uint4* gb = reinterpret_cast<const uint4*>(&W[(size_t)(n0 + sr) * HDIM + kb + sh]);
      uint4* lb = reinterpret_cast<uint4*>(&Bs[sr][sh]);
      lb[0] = gb[0]; lb[1] = gb[1]; lb[2] = gb[2]; lb[3] = gb[3];
    }
    __syncthreads();
#pragma unroll
    for (int ks = 0; ks < 2; ++ks) {
      const int ko = ks * 32 + lk;
      bfrag af[4], bfv[4];
#pragma unroll
      for (int i = 0; i < 4; ++i)
        af[i] = *reinterpret_cast<const bfrag*>(&As[wm + i * 16 + lr][ko]);
#pragma unroll
      for (int j = 0; j < 4; ++j)
        bfv[j] = *reinterpret_cast<const bfrag*>(&Bs[wn + j * 16 + lr][ko]);
#pragma unroll
      for (int i = 0; i < 4; ++i)
#pragma unroll
        for (int j = 0; j < 4; ++j)
          acc[i][j] = mfma16(af[i], bfv[j], acc[i][j]);
    }
  }
  const int rg = (l >> 4) * 4;
#pragma unroll
  for (int j = 0; j < 4; ++j) {
    const int n = n0 + wn + j * 16 + lr;
    const float bias = bih[n] + bhh[n];
    const int g = (n & 1023) >> 2;                 // owning recurrence WG
    const int p = ((n >> 10) << 2) | (n & 3);      // slot within WG's 16 cols
    bf16* base = xg + (size_t)g * TSTEPS * BATCH * 16;
#pragma unroll
    for (int i = 0; i < 4; ++i) {
#pragma unroll
      for (int r = 0; r < 4; ++r) {
        const int m = m0 + wm + i * 16 + rg + r;
        const int b = m >> 8, t = m & 255;   // m = b*256 + t
        base[((size_t)t * BATCH + b) * 16 + p] = f2b(acc[i][j][r] + bias);
      }
    }
  }
}

// ---------------- persistent LSTM recurrence ----------------
// 256 WGs x 512 threads (8 waves). WG g owns hidden cols j0=4g..4g+3 => 16 gate
// cols (slot p: q=p>>2, jj=p&3 -> gcol = q*1024 + j0 + jj).
// Wave w: batch group bg=w>>1 (rows 16bg..16bg+15), K-half kh=w&1 (k in [512kh,512kh+512)).
// Partial gates combined in LDS. Elementwise by wave 0 (tid<64).
// Barrier: packed contiguous flags (coalesced poll), wave0-internal arrival.
__launch_bounds__(512, 1)
__global__ void lstm_seq_kernel(const bf16* __restrict__ xg,   // (wg,t,b,16)
                                const bf16* __restrict__ Whh,  // (4096,1024) bf16
                                bf16* h0, bf16* h1,            // ping-pong h
                                bf16* __restrict__ ys,         // (B,T,H) layer output
                                float* __restrict__ out_h,
                                float* __restrict__ out_c,
                                float* __restrict__ out_last,  // null except last layer
                                unsigned* __restrict__ flags) {
  __shared__ bf16 lw[16][HDIM + 8];     // W_hh rows for the 16 gate cols (33 KB)
  __shared__ float gxp[2][BATCH][21];   // K-half partial gates (odd stride: no conflicts)
  const int wg = blockIdx.x;
  const int tid = threadIdx.x;
  const int w = tid >> 6, l = tid & 63;
  const int j0 = wg * 4;

  // stage this WG's 16 W_hh rows into LDS (once): 16 rows x 2048B, 32 thr/row x 4 uint4
  {
    const int p = tid >> 5, li = tid & 31;
    const int gcol = (p >> 2) * HDIM + j0 + (p & 3);
    const uint4* src = reinterpret_cast<const uint4*>(&Whh[(size_t)gcol * HDIM]);
    uint4* dst = reinterpret_cast<uint4*>(&lw[p][0]);
#pragma unroll
    for (int kk = 0; kk < 4; ++kk) dst[li * 4 + kk] = src[li * 4 + kk];
  }

  // elementwise ownership (wave 0): thread eb=tid owns batch eb, cols j0..j0+3
  const int eb = tid;
  float c0 = 0.f, c1 = 0.f, c2 = 0.f, c3 = 0.f;

  // init h0 slice, then global barrier epoch 1
  if (tid < 64)
    store_u64_agent((unsigned long long*)&h0[(size_t)eb * HDIM + j0], 0ull);
  __builtin_amdgcn_s_waitcnt(0);
  if (tid == 0) store_u32_agent(&flags[wg], 1u);
  if (tid < 128) {
    const unsigned long long* f2 = (const unsigned long long*)flags;
    for (;;) {
      unsigned long long v = load_u64_agent(&f2[tid]);
      if ((unsigned)v >= 1u && (unsigned)(v >> 32) >= 1u) break;
      __builtin_amdgcn_s_sleep(1);
    }
  }
  __syncthreads();
  __builtin_amdgcn_sched_barrier(0);

  const int lr = l & 15, lk = (l >> 4) * 8;
  const int rg = (l >> 4) * 4;
  const int bg = w >> 1, kh = w & 1;
  const int kbase = kh * 512;
  const bf16* xgw = xg + (size_t)wg * TSTEPS * BATCH * 16;

  // prefetch xg(t=0) for kh==0 waves: 4 rows x 1 col each
  unsigned short xn[4];
  if (kh == 0) {
    const unsigned short* xt = (const unsigned short*)xgw;
#pragma unroll
    for (int r = 0; r < 4; ++r) xn[r] = xt[(16 * bg + rg + r) * 16 + lr];
  }

  for (int t = 0; t < TSTEPS; ++t) {
    const bf16* hin  = (t & 1) ? h1 : h0;
    bf16*       hout = (t & 1) ? h0 : h1;
    ffrag acc = ffrag{0.f, 0.f, 0.f, 0.f};
    const unsigned long long* hrow =
        (const unsigned long long*)&hin[(size_t)(16 * bg + lr) * HDIM + kbase];
#pragma unroll 8
    for (int ks = 0; ks < 16; ++ks) {
      const int off = (ks * 32 + lk) >> 2;   // u64 index (4 bf16 each)
      union { unsigned long long u[2]; bfrag f; } au;
      au.u[0] = load_u64_agent(hrow + off);
      au.u[1] = load_u64_agent(hrow + off + 1);
      bfrag bv = *reinterpret_cast<const bfrag*>(&lw[lr][kbase + ks * 32 + lk]);
      acc = mfma16(au.f, bv, acc);
    }
    // store partial gates (kh0 folds in xg), then prefetch next xg
    if (kh == 0) {
#pragma unroll
      for (int r = 0; r < 4; ++r)
        gxp[0][16 * bg + rg + r][lr] = acc[r] + bs2f(xn[r]);
      const int tn = (t + 1 < TSTEPS) ? t + 1 : t;
      const unsigned short* xt = (const unsigned short*)(xgw + (size_t)tn * BATCH * 16);
#pragma unroll
      for (int r = 0; r < 4; ++r) xn[r] = xt[(16 * bg + rg + r) * 16 + lr];
    } else {
#pragma unroll
      for (int r = 0; r < 4; ++r)
        gxp[1][16 * bg + rg + r][lr] = acc[r];
    }
    __syncthreads();   // gxp ready
    // elementwise: wave 0 only (one batch row per thread)
    if (tid < 64) {
      float hnew[4], cc[4] = {c0, c1, c2, c3};
      union { unsigned short s[4]; unsigned long long u; } pk;
#pragma unroll
      for (int m = 0; m < 4; ++m) {
        const float gi = gxp[0][eb][0 + m]  + gxp[1][eb][0 + m];
        const float gf = gxp[0][eb][4 + m]  + gxp[1][eb][4 + m];
        const float gg = gxp[0][eb][8 + m]  + gxp[1][eb][8 + m];
        const float go = gxp[0][eb][12 + m] + gxp[1][eb][12 + m];
        const float iv = sigm(gi), fv = sigm(gf), gv = tanhfast(gg), ov = sigm(go);
        cc[m] = fv * cc[m] + iv * gv;
        hnew[m] = ov * tanhfast(cc[m]);
        pk.s[m] = (unsigned short)f2bs(hnew[m]);
      }
      c0 = cc[0]; c1 = cc[1]; c2 = cc[2]; c3 = cc[3];
      store_u64_agent((unsigned long long*)&hout[(size_t)eb * HDIM + j0], pk.u);
      *(unsigned long long*)&ys[((size_t)eb * TSTEPS + t) * HDIM + j0] = pk.u;
      if (t == TSTEPS - 1) {
        float4 hv = {hnew[0], hnew[1], hnew[2], hnew[3]};
        float4 cv = {cc[0], cc[1], cc[2], cc[3]};
        *reinterpret_cast<float4*>(&out_h[(size_t)eb * HDIM + j0]) = hv;
        *reinterpret_cast<float4*>(&out_c[(size_t)eb * HDIM + j0]) = cv;
        if (out_last) *reinterpret_cast<float4*>(&out_last[(size_t)eb * HDIM + j0]) = hv;
      }
    }
    if (t + 1 < TSTEPS) {
      const unsigned ep = (unsigned)(t + 2);
      __builtin_amdgcn_s_waitcnt(0);       // wave0: h stores acked at coherence point
      if (tid == 0) store_u32_agent(&flags[wg], ep);
      if (tid < 128) {
        const unsigned long long* f2 = (const unsigned long long*)flags;
        for (;;) {
          unsigned long long v = load_u64_agent(&f2[tid]);
          if ((unsigned)v >= ep && (unsigned)(v >> 32) >= ep) break;
          __builtin_amdgcn_s_sleep(1);
        }
      }
      __syncthreads();
      __builtin_amdgcn_sched_barrier(0);
    }
  }
}

// ---------------- logits = h_T @ W_proj^T + b_proj ----------------
__launch_bounds__(256, 2)
__global__ void logits_kernel(const bf16* __restrict__ hfin,  // (64,1024) bf16
                              const float* __restrict__ Wp,   // (32000,1024) f32
                              const float* __restrict__ bp,
                              float* __restrict__ out) {      // (64,32000)
  const int tid = threadIdx.x;
  const int w = tid >> 6, l = tid & 63;
  const int lr = l & 15, lk = (l >> 4) * 8;
  const int col = blockIdx.x * 64 + w * 16 + lr;
  const float* wrow = &Wp[(size_t)col * HDIM];
  ffrag acc[4];
#pragma unroll
  for (int i = 0; i < 4; ++i) acc[i] = ffrag{0.f, 0.f, 0.f, 0.f};
#pragma unroll 2
  for (int ks = 0; ks < 32; ++ks) {
    const int k = ks * 32 + lk;
    float4 wa = *reinterpret_cast<const float4*>(&wrow[k]);
    float4 wb = *reinterpret_cast<const float4*>(&wrow[k + 4]);
    bfrag bv;
    bv[0] = f2bs(wa.x); bv[1] = f2bs(wa.y); bv[2] = f2bs(wa.z); bv[3] = f2bs(wa.w);
    bv[4] = f2bs(wb.x); bv[5] = f2bs(wb.y); bv[6] = f2bs(wb.z); bv[7] = f2bs(wb.w);
#pragma unroll
    for (int i = 0; i < 4; ++i) {
      bfrag av = *reinterpret_cast<const bfrag*>(&hfin[(size_t)(i * 16 + lr) * HDIM + k]);
      acc[i] = mfma16(av, bv, acc[i]);
    }
  }
  const float bias = bp[col];
#pragma unroll
  for (int i = 0; i < 4; ++i) {
#pragma unroll
    for (int r = 0; r < 4; ++r) {
      const int b = i * 16 + (l >> 4) * 4 + r;
      out[(size_t)b * VOCAB + col] = acc[i][r] + bias;
    }
  }
}

extern "C" void kernel_launch(void* const* d_in, const int* in_sizes, int n_in,
                              void* d_out, int out_size, void* d_ws, size_t ws_size,
                              hipStream_t stream) {
  const int*   ids   = (const int*)d_in[0];
  const float* table = (const float*)d_in[1];
  const float* Wih   = (const float*)d_in[2];
  const float* Whh   = (const float*)d_in[3];
  const float* bih   = (const float*)d_in[4];
  const float* bhh   = (const float*)d_in[5];
  const float* Wp    = (const float*)d_in[6];
  const float* bp    = (const float*)d_in[7];
  float* out = (float*)d_out;

  char* ws = (char*)d_ws;
  const size_t OFF_XG  = 0;
  const size_t OFF_X   = OFF_XG  + (size_t)NWG_SEQ * TSTEPS * BATCH * 16 * 2;  // 128 MB
  const size_t OFF_WIH = OFF_X   + (size_t)BATCH * TSTEPS * HDIM * 2;
  const size_t OFF_WHH = OFF_WIH + (size_t)2 * GDIM * HDIM * 2;
  const size_t OFF_SYNC= OFF_WHH + (size_t)2 * GDIM * HDIM * 2;
  const size_t OFF_H0  = OFF_SYNC+ (size_t)65536;
  const size_t OFF_H1  = OFF_H0  + (size_t)BATCH * HDIM * 2;

  bf16* xg    = (bf16*)(ws + OFF_XG);
  bf16* xb    = (bf16*)(ws + OFF_X);
  bf16* wihb  = (bf16*)(ws + OFF_WIH);
  bf16* whhb  = (bf16*)(ws + OFF_WHH);
  unsigned* sync = (unsigned*)(ws + OFF_SYNC);
  bf16* h0    = (bf16*)(ws + OFF_H0);
  bf16* h1    = (bf16*)(ws + OFF_H1);

  (void)hipMemsetAsync(sync, 0, 65536, stream);

  const int nconv4 = 2 * GDIM * HDIM / 4;
  convert_bf16_kernel<<<nconv4 / 256, 256, 0, stream>>>(Wih, wihb, nconv4);
  convert_bf16_kernel<<<nconv4 / 256, 256, 0, stream>>>(Whh, whhb, nconv4);
  const int nemb4 = BATCH * TSTEPS * HDIM / 4;
  embed_kernel<<<nemb4 / 256, 256, 0, stream>>>(ids, table, xb, nemb4);

  float* out_last   = out;              // (64,1024)
  float* out_logits = out + 65536;      // (64,32000)
  float* out_hn     = out + 2113536;    // (2,64,1024)
  float* out_cn     = out + 2244608;    // (2,64,1024)

  for (int lyr = 0; lyr < 2; ++lyr) {
    gemm_xg_kernel<<<dim3(GDIM / BNX, (BATCH * TSTEPS) / BMX), 256, 0, stream>>>(
        xb, wihb + (size_t)lyr * GDIM * HDIM, bih + lyr * GDIM, bhh + lyr * GDIM, xg);
    unsigned* flags = sync + (size_t)lyr * 1024;
    lstm_seq_kernel<<<NWG_SEQ, 512, 0, stream>>>(
        xg, whhb + (size_t)lyr * GDIM * HDIM, h0, h1, xb,
        out_hn + (size_t)lyr * BATCH * HDIM, out_cn + (size_t)lyr * BATCH * HDIM,
        (lyr == 1) ? out_last : nullptr, flags);
  }
  logits_kernel<<<VOCAB / 64, 256, 0, stream>>>(h0, Wp, bp, out_logits);
}

// Round 5
// 6154.216 us; speedup vs baseline: 1.2040x; 1.2040x over previous
//
#include <hip/hip_runtime.h>
#include <hip/hip_bf16.h>
#include <stdint.h>
#include <stddef.h>

typedef __hip_bfloat16 bf16;
typedef __attribute__((ext_vector_type(8))) short bfrag;
typedef __attribute__((ext_vector_type(4))) float ffrag;

#define HDIM 1024
#define BATCH 64
#define TSTEPS 256
#define GDIM 4096
#define VOCAB 32000
#define NWG_SEQ 128   // 128 WGs x 512 threads; WG owns 8 hidden cols (32 gate cols)

__device__ __forceinline__ float b2f(bf16 x) { return __bfloat162float(x); }
__device__ __forceinline__ bf16 f2b(float x) { return __float2bfloat16(x); }
__device__ __forceinline__ short f2bs(float x) {
  bf16 b = __float2bfloat16(x);
  return *reinterpret_cast<short*>(&b);
}
__device__ __forceinline__ float bs2f(unsigned short u) {
  union { unsigned int i; float f; } v;
  v.i = ((unsigned int)u) << 16;
  return v.f;
}
__device__ __forceinline__ ffrag mfma16(bfrag a, bfrag b, ffrag c) {
  return __builtin_amdgcn_mfma_f32_16x16x32_bf16(a, b, c, 0, 0, 0);
}
__device__ __forceinline__ float sigm(float x) { return 1.0f / (1.0f + __expf(-x)); }
__device__ __forceinline__ float tanhfast(float x) {
  float e = __expf(2.0f * x);
  return 1.0f - 2.0f / (e + 1.0f);
}

// agent-scope point-coherent ops (write-through to MALL / bypass stale caches)
__device__ __forceinline__ void store_u64_agent(unsigned long long* p, unsigned long long v) {
  __hip_atomic_store(p, v, __ATOMIC_RELAXED, __HIP_MEMORY_SCOPE_AGENT);
}
__device__ __forceinline__ unsigned long long load_u64_agent(const unsigned long long* p) {
  return __hip_atomic_load(p, __ATOMIC_RELAXED, __HIP_MEMORY_SCOPE_AGENT);
}
__device__ __forceinline__ void store_u32_agent(unsigned* p, unsigned v) {
  __hip_atomic_store(p, v, __ATOMIC_RELAXED, __HIP_MEMORY_SCOPE_AGENT);
}

// ---------------- convert f32 -> bf16 ----------------
__global__ void convert_bf16_kernel(const float* __restrict__ src, bf16* __restrict__ dst, int n4) {
  int i = blockIdx.x * 256 + threadIdx.x;
  if (i >= n4) return;
  float4 v = reinterpret_cast<const float4*>(src)[i];
  ushort4 o;
  o.x = (unsigned short)f2bs(v.x);
  o.y = (unsigned short)f2bs(v.y);
  o.z = (unsigned short)f2bs(v.z);
  o.w = (unsigned short)f2bs(v.w);
  reinterpret_cast<ushort4*>(dst)[i] = o;
}

// ---------------- embedding gather -> bf16 ----------------
__global__ void embed_kernel(const int* __restrict__ ids, const float* __restrict__ table,
                             bf16* __restrict__ x, int n4) {
  int i = blockIdx.x * 256 + threadIdx.x;
  if (i >= n4) return;
  int row = i >> 8;   // H/4 = 256 float4 per (b,t) row
  int c4 = i & 255;
  int tok = ids[row];
  float4 v = reinterpret_cast<const float4*>(table)[(size_t)tok * 256 + c4];
  ushort4 o;
  o.x = (unsigned short)f2bs(v.x);
  o.y = (unsigned short)f2bs(v.y);
  o.z = (unsigned short)f2bs(v.z);
  o.w = (unsigned short)f2bs(v.w);
  reinterpret_cast<ushort4*>(x)[i] = o;
}

// ---------------- xg = x @ W_ih^T + b_ih + b_hh ----------------
// A: (16384,1024) bf16 K-major; W: (4096,1024) bf16 K-major.
// out xg layout: (wg, t, b, 32) -- per-recurrence-WG contiguous.
#define BMX 128
#define BNX 128
#define BKX 64

__launch_bounds__(256, 2)
__global__ void gemm_xg_kernel(const bf16* __restrict__ A,
                               const bf16* __restrict__ W,
                               const float* __restrict__ bih,
                               const float* __restrict__ bhh,
                               bf16* __restrict__ xg) {
  __shared__ bf16 As[BMX][BKX + 8];
  __shared__ bf16 Bs[BNX][BKX + 8];
  const int n0 = blockIdx.x * BNX;
  const int m0 = blockIdx.y * BMX;
  const int tid = threadIdx.x;
  const int w = tid >> 6, l = tid & 63;
  const int wm = (w >> 1) * 64, wn = (w & 1) * 64;
  const int lr = l & 15, lk = (l >> 4) * 8;

  ffrag acc[4][4];
#pragma unroll
  for (int i = 0; i < 4; ++i)
#pragma unroll
    for (int j = 0; j < 4; ++j) acc[i][j] = ffrag{0.f, 0.f, 0.f, 0.f};

  const int sr = tid >> 1, sh = (tid & 1) * 32;
  for (int kb = 0; kb < HDIM; kb += BKX) {
    __syncthreads();
    {
      const uint4* ga = reinterpret_cast<const uint4*>(&A[(size_t)(m0 + sr) * HDIM + kb + sh]);
      uint4* la = reinterpret_cast<uint4*>(&As[sr][sh]);
      la[0] = ga[0]; la[1] = ga[1]; la[2] = ga[2]; la[3] = ga[3];
      const uint4* gb = reinterpret_cast<const uint4*>(&W[(size_t)(n0 + sr) * HDIM + kb + sh]);
      uint4* lb = reinterpret_cast<uint4*>(&Bs[sr][sh]);
      lb[0] = gb[0]; lb[1] = gb[1]; lb[2] = gb[2]; lb[3] = gb[3];
    }
    __syncthreads();
#pragma unroll
    for (int ks = 0; ks < 2; ++ks) {
      const int ko = ks * 32 + lk;
      bfrag af[4], bfv[4];
#pragma unroll
      for (int i = 0; i < 4; ++i)
        af[i] = *reinterpret_cast<const bfrag*>(&As[wm + i * 16 + lr][ko]);
#pragma unroll
      for (int j = 0; j < 4; ++j)
        bfv[j] = *reinterpret_cast<const bfrag*>(&Bs[wn + j * 16 + lr][ko]);
#pragma unroll
      for (int i = 0; i < 4; ++i)
#pragma unroll
        for (int j = 0; j < 4; ++j)
          acc[i][j] = mfma16(af[i], bfv[j], acc[i][j]);
    }
  }
  const int rg = (l >> 4) * 4;
#pragma unroll
  for (int j = 0; j < 4; ++j) {
    const int n = n0 + wn + j * 16 + lr;
    const float bias = bih[n] + bhh[n];
    const int g = (n & 1023) >> 3;                 // owning recurrence WG
    const int p = ((n >> 10) << 3) | (n & 7);      // slot within WG's 32 cols
    bf16* base = xg + (size_t)g * TSTEPS * BATCH * 32;
#pragma unroll
    for (int i = 0; i < 4; ++i) {
#pragma unroll
      for (int r = 0; r < 4; ++r) {
        const int m = m0 + wm + i * 16 + rg + r;
        const int b = m >> 8, t = m & 255;   // m = b*256 + t
        base[((size_t)t * BATCH + b) * 32 + p] = f2b(acc[i][j][r] + bias);
      }
    }
  }
}

// ---------------- persistent LSTM recurrence ----------------
// 128 WGs x 512 threads (8 waves). WG g owns hidden cols j0=8g..8g+7 => 32 gate
// cols (slot p: q=p>>3, jj=p&7 -> gcol = q*1024 + j0 + jj).
// Wave w: batch group bg=w>>1 (rows 16bg..16bg+15), K-half kh=w&1.
// W_hh fragments live in REGISTERS (32 bfrags/lane). K-half partials in LDS.
// h write: relaxed sc1 (to MALL). h read: CACHED loads, made safe by one
// agent-acquire fence (buffer_inv, invalidate-only) per WG per step.
__launch_bounds__(512, 2)
__global__ void lstm_seq_kernel(const bf16* __restrict__ xg,   // (wg,t,b,32)
                                const bf16* __restrict__ Whh,  // (4096,1024) bf16
                                bf16* h0, bf16* h1,            // ping-pong h
                                bf16* __restrict__ ys,         // (B,T,H) layer output
                                float* __restrict__ out_h,
                                float* __restrict__ out_c,
                                float* __restrict__ out_last,  // null except last layer
                                unsigned* __restrict__ flags) {
  __shared__ float gxp[2][BATCH][37];   // K-half partial gates
  const int wg = blockIdx.x;
  const int tid = threadIdx.x;
  const int w = tid >> 6, l = tid & 63;
  const int lr = l & 15, lkg = l >> 4;
  const int bg = w >> 1, kh = w & 1;
  const int kbase = kh * 512;
  const int j0 = wg * 8;

  // --- W_hh fragments into registers (once): 2 col-tiles x 16 k-steps ---
  bfrag breg0[16], breg1[16];
  {
    const int p0 = lr, p1 = 16 + lr;
    const size_t r0 = (size_t)((p0 >> 3) * HDIM + j0 + (p0 & 7)) * HDIM;
    const size_t r1 = (size_t)((p1 >> 3) * HDIM + j0 + (p1 & 7)) * HDIM;
#pragma unroll
    for (int ks = 0; ks < 16; ++ks) {
      breg0[ks] = *reinterpret_cast<const bfrag*>(&Whh[r0 + kbase + ks * 32 + lkg * 8]);
      breg1[ks] = *reinterpret_cast<const bfrag*>(&Whh[r1 + kbase + ks * 32 + lkg * 8]);
    }
  }

  // elementwise ownership: tid<128 -> batch eb=tid&63, 4 cols at j0+ej
  const int eb = tid & 63;
  const int ej = (tid >> 6) * 4;
  float c0 = 0.f, c1 = 0.f, c2 = 0.f, c3 = 0.f;

  // init h0 slice, then epoch-1 barrier
  if (tid < 128)
    store_u64_agent((unsigned long long*)&h0[(size_t)eb * HDIM + j0 + ej], 0ull);
  __builtin_amdgcn_s_waitcnt(0);
  if (tid == 0)  store_u32_agent(&flags[2 * wg], 1u);
  if (tid == 64) store_u32_agent(&flags[2 * wg + 1], 1u);
  if (tid < 128) {
    const unsigned long long* f2 = (const unsigned long long*)flags;
    for (;;) {
      unsigned long long v = load_u64_agent(&f2[tid]);
      if ((unsigned)v >= 1u && (unsigned)(v >> 32) >= 1u) break;
      __builtin_amdgcn_s_sleep(1);
    }
  }
  __syncthreads();
  if (w == 0) {
    __builtin_amdgcn_fence(__ATOMIC_ACQUIRE, "agent");  // buffer_inv (no writeback)
    __builtin_amdgcn_s_waitcnt(0);
  }
  __syncthreads();
  __builtin_amdgcn_sched_barrier(0);

  const bf16* xgw = xg + (size_t)wg * TSTEPS * BATCH * 32;

  // prefetch xg(t=0): kh==0 waves fold xg; 4 rows x 2 col-tiles per lane
  unsigned short xn0[4], xn1[4];
  if (kh == 0) {
    const unsigned short* xt = (const unsigned short*)xgw;
#pragma unroll
    for (int r = 0; r < 4; ++r) {
      const int b = 16 * bg + lkg * 4 + r;
      xn0[r] = xt[b * 32 + lr];
      xn1[r] = xt[b * 32 + 16 + lr];
    }
  }

  for (int t = 0; t < TSTEPS; ++t) {
    const bf16* hin  = (t & 1) ? h1 : h0;
    bf16*       hout = (t & 1) ? h0 : h1;
    ffrag acc0 = ffrag{0.f, 0.f, 0.f, 0.f};
    ffrag acc1 = ffrag{0.f, 0.f, 0.f, 0.f};
    // cached A loads: lane's batch row, this wave's K-half
    const char* hrow = (const char*)&hin[(size_t)(16 * bg + lr) * HDIM + kbase];
#pragma unroll
    for (int ks = 0; ks < 16; ++ks) {
      bfrag a = *reinterpret_cast<const bfrag*>(hrow + ks * 64 + lkg * 16);
      acc0 = mfma16(a, breg0[ks], acc0);
      acc1 = mfma16(a, breg1[ks], acc1);
    }
    if (kh == 0) {
#pragma unroll
      for (int r = 0; r < 4; ++r) {
        const int b = 16 * bg + lkg * 4 + r;
        gxp[0][b][lr]      = acc0[r] + bs2f(xn0[r]);
        gxp[0][b][16 + lr] = acc1[r] + bs2f(xn1[r]);
      }
      // prefetch next step's xg (constant data; hides latency under barrier)
      const int tn = (t + 1 < TSTEPS) ? t + 1 : t;
      const unsigned short* xt = (const unsigned short*)(xgw + (size_t)tn * BATCH * 32);
#pragma unroll
      for (int r = 0; r < 4; ++r) {
        const int b = 16 * bg + lkg * 4 + r;
        xn0[r] = xt[b * 32 + lr];
        xn1[r] = xt[b * 32 + 16 + lr];
      }
    } else {
#pragma unroll
      for (int r = 0; r < 4; ++r) {
        const int b = 16 * bg + lkg * 4 + r;
        gxp[1][b][lr]      = acc0[r];
        gxp[1][b][16 + lr] = acc1[r];
      }
    }
    __syncthreads();   // gxp ready
    if (tid < 128) {
      float hnew[4], cc[4] = {c0, c1, c2, c3};
      union { unsigned short s[4]; unsigned long long u; } pk;
#pragma unroll
      for (int m = 0; m < 4; ++m) {
        const int jc = ej + m;
        const float gi = gxp[0][eb][jc]      + gxp[1][eb][jc];
        const float gf = gxp[0][eb][8 + jc]  + gxp[1][eb][8 + jc];
        const float gg = gxp[0][eb][16 + jc] + gxp[1][eb][16 + jc];
        const float go = gxp[0][eb][24 + jc] + gxp[1][eb][24 + jc];
        const float iv = sigm(gi), fv = sigm(gf), gv = tanhfast(gg), ov = sigm(go);
        cc[m] = fv * cc[m] + iv * gv;
        hnew[m] = ov * tanhfast(cc[m]);
        pk.s[m] = (unsigned short)f2bs(hnew[m]);
      }
      c0 = cc[0]; c1 = cc[1]; c2 = cc[2]; c3 = cc[3];
      store_u64_agent((unsigned long long*)&hout[(size_t)eb * HDIM + j0 + ej], pk.u);
      *(unsigned long long*)&ys[((size_t)eb * TSTEPS + t) * HDIM + j0 + ej] = pk.u;
      if (t == TSTEPS - 1) {
        float4 hv = {hnew[0], hnew[1], hnew[2], hnew[3]};
        float4 cv = {cc[0], cc[1], cc[2], cc[3]};
        *reinterpret_cast<float4*>(&out_h[(size_t)eb * HDIM + j0 + ej]) = hv;
        *reinterpret_cast<float4*>(&out_c[(size_t)eb * HDIM + j0 + ej]) = cv;
        if (out_last) *reinterpret_cast<float4*>(&out_last[(size_t)eb * HDIM + j0 + ej]) = hv;
      } else {
        __builtin_amdgcn_s_waitcnt(0);   // this wave's h stores acked at MALL
        const unsigned ep = (unsigned)(t + 2);
        if (tid == 0)  store_u32_agent(&flags[2 * wg], ep);
        if (tid == 64) store_u32_agent(&flags[2 * wg + 1], ep);
        const unsigned long long* f2 = (const unsigned long long*)flags;
        for (;;) {
          unsigned long long v = load_u64_agent(&f2[tid]);
          if ((unsigned)v >= ep && (unsigned)(v >> 32) >= ep) break;
          __builtin_amdgcn_s_sleep(1);
        }
      }
    }
    if (t + 1 < TSTEPS) {
      __syncthreads();                   // pollers done: all WGs' h(t) at MALL
      if (w == 0) {
        __builtin_amdgcn_fence(__ATOMIC_ACQUIRE, "agent");  // invalidate L1+L2 h lines
        __builtin_amdgcn_s_waitcnt(0);
      }
      __syncthreads();
      __builtin_amdgcn_sched_barrier(0);
    }
  }
}

// ---------------- logits = h_T @ W_proj^T + b_proj ----------------
__launch_bounds__(256, 2)
__global__ void logits_kernel(const bf16* __restrict__ hfin,  // (64,1024) bf16
                              const float* __restrict__ Wp,   // (32000,1024) f32
                              const float* __restrict__ bp,
                              float* __restrict__ out) {      // (64,32000)
  const int tid = threadIdx.x;
  const int w = tid >> 6, l = tid & 63;
  const int lr = l & 15, lk = (l >> 4) * 8;
  const int col = blockIdx.x * 64 + w * 16 + lr;
  const float* wrow = &Wp[(size_t)col * HDIM];
  ffrag acc[4];
#pragma unroll
  for (int i = 0; i < 4; ++i) acc[i] = ffrag{0.f, 0.f, 0.f, 0.f};
#pragma unroll 2
  for (int ks = 0; ks < 32; ++ks) {
    const int k = ks * 32 + lk;
    float4 wa = *reinterpret_cast<const float4*>(&wrow[k]);
    float4 wb = *reinterpret_cast<const float4*>(&wrow[k + 4]);
    bfrag bv;
    bv[0] = f2bs(wa.x); bv[1] = f2bs(wa.y); bv[2] = f2bs(wa.z); bv[3] = f2bs(wa.w);
    bv[4] = f2bs(wb.x); bv[5] = f2bs(wb.y); bv[6] = f2bs(wb.z); bv[7] = f2bs(wb.w);
#pragma unroll
    for (int i = 0; i < 4; ++i) {
      bfrag av = *reinterpret_cast<const bfrag*>(&hfin[(size_t)(i * 16 + lr) * HDIM + k]);
      acc[i] = mfma16(av, bv, acc[i]);
    }
  }
  const float bias = bp[col];
#pragma unroll
  for (int i = 0; i < 4; ++i) {
#pragma unroll
    for (int r = 0; r < 4; ++r) {
      const int b = i * 16 + (l >> 4) * 4 + r;
      out[(size_t)b * VOCAB + col] = acc[i][r] + bias;
    }
  }
}

extern "C" void kernel_launch(void* const* d_in, const int* in_sizes, int n_in,
                              void* d_out, int out_size, void* d_ws, size_t ws_size,
                              hipStream_t stream) {
  const int*   ids   = (const int*)d_in[0];
  const float* table = (const float*)d_in[1];
  const float* Wih   = (const float*)d_in[2];
  const float* Whh   = (const float*)d_in[3];
  const float* bih   = (const float*)d_in[4];
  const float* bhh   = (const float*)d_in[5];
  const float* Wp    = (const float*)d_in[6];
  const float* bp    = (const float*)d_in[7];
  float* out = (float*)d_out;

  char* ws = (char*)d_ws;
  const size_t OFF_XG  = 0;
  const size_t OFF_X   = OFF_XG  + (size_t)NWG_SEQ * TSTEPS * BATCH * 32 * 2;  // 128 MB
  const size_t OFF_WIH = OFF_X   + (size_t)BATCH * TSTEPS * HDIM * 2;
  const size_t OFF_WHH = OFF_WIH + (size_t)2 * GDIM * HDIM * 2;
  const size_t OFF_SYNC= OFF_WHH + (size_t)2 * GDIM * HDIM * 2;
  const size_t OFF_H0  = OFF_SYNC+ (size_t)65536;
  const size_t OFF_H1  = OFF_H0  + (size_t)BATCH * HDIM * 2;

  bf16* xg    = (bf16*)(ws + OFF_XG);
  bf16* xb    = (bf16*)(ws + OFF_X);
  bf16* wihb  = (bf16*)(ws + OFF_WIH);
  bf16* whhb  = (bf16*)(ws + OFF_WHH);
  unsigned* sync = (unsigned*)(ws + OFF_SYNC);
  bf16* h0    = (bf16*)(ws + OFF_H0);
  bf16* h1    = (bf16*)(ws + OFF_H1);

  (void)hipMemsetAsync(sync, 0, 65536, stream);

  const int nconv4 = 2 * GDIM * HDIM / 4;
  convert_bf16_kernel<<<nconv4 / 256, 256, 0, stream>>>(Wih, wihb, nconv4);
  convert_bf16_kernel<<<nconv4 / 256, 256, 0, stream>>>(Whh, whhb, nconv4);
  const int nemb4 = BATCH * TSTEPS * HDIM / 4;
  embed_kernel<<<nemb4 / 256, 256, 0, stream>>>(ids, table, xb, nemb4);

  float* out_last   = out;              // (64,1024)
  float* out_logits = out + 65536;      // (64,32000)
  float* out_hn     = out + 2113536;    // (2,64,1024)
  float* out_cn     = out + 2244608;    // (2,64,1024)

  for (int lyr = 0; lyr < 2; ++lyr) {
    gemm_xg_kernel<<<dim3(GDIM / BNX, (BATCH * TSTEPS) / BMX), 256, 0, stream>>>(
        xb, wihb + (size_t)lyr * GDIM * HDIM, bih + lyr * GDIM, bhh + lyr * GDIM, xg);
    unsigned* flags = sync + (size_t)lyr * 512;
    lstm_seq_kernel<<<NWG_SEQ, 512, 0, stream>>>(
        xg, whhb + (size_t)lyr * GDIM * HDIM, h0, h1, xb,
        out_hn + (size_t)lyr * BATCH * HDIM, out_cn + (size_t)lyr * BATCH * HDIM,
        (lyr == 1) ? out_last : nullptr, flags);
  }
  logits_kernel<<<VOCAB / 64, 256, 0, stream>>>(h0, Wp, bp, out_logits);
}

// Round 6
// 3585.542 us; speedup vs baseline: 2.0665x; 1.7164x over previous
//
#include <hip/hip_runtime.h>
#include <hip/hip_bf16.h>
#include <stdint.h>
#include <stddef.h>

typedef __hip_bfloat16 bf16;
typedef __attribute__((ext_vector_type(8))) short bfrag;
typedef __attribute__((ext_vector_type(4))) float ffrag;

#define HDIM 1024
#define BATCH 64
#define TSTEPS 256
#define GDIM 4096
#define VOCAB 32000
#define NWG_SEQ 128   // 128 WGs x 512 threads; WG g owns hidden cols 8g..8g+7

// xg element layout: ((q*128 + g)*16384 + idx)*8 + jj   (q=gate, g=WG, jj=col&7)
//   layer 1: idx = b*256 + t ; layer 2: idx = t*64 + b  (matches gemm m-order)
#define QOFF ((size_t)128 * 16384 * 8)
// hT layout: u64 index (half*8192 + kg*64 + b); half = (col&7)>>2, kg = col>>3

__device__ __forceinline__ float b2f(bf16 x) { return __bfloat162float(x); }
__device__ __forceinline__ bf16 f2b(float x) { return __float2bfloat16(x); }
__device__ __forceinline__ short f2bs(float x) {
  bf16 b = __float2bfloat16(x);
  return *reinterpret_cast<short*>(&b);
}
__device__ __forceinline__ float bs2f(unsigned short u) {
  union { unsigned int i; float f; } v;
  v.i = ((unsigned int)u) << 16;
  return v.f;
}
__device__ __forceinline__ ffrag mfma16(bfrag a, bfrag b, ffrag c) {
  return __builtin_amdgcn_mfma_f32_16x16x32_bf16(a, b, c, 0, 0, 0);
}
__device__ __forceinline__ float sigm(float x) { return 1.0f / (1.0f + __expf(-x)); }
__device__ __forceinline__ float tanhfast(float x) {
  float e = __expf(2.0f * x);
  return 1.0f - 2.0f / (e + 1.0f);
}

// agent-scope point-coherent ops (write-through to MALL / bypass stale caches)
__device__ __forceinline__ void store_u64_agent(unsigned long long* p, unsigned long long v) {
  __hip_atomic_store(p, v, __ATOMIC_RELAXED, __HIP_MEMORY_SCOPE_AGENT);
}
__device__ __forceinline__ unsigned long long load_u64_agent(const unsigned long long* p) {
  return __hip_atomic_load(p, __ATOMIC_RELAXED, __HIP_MEMORY_SCOPE_AGENT);
}
__device__ __forceinline__ void store_u32_agent(unsigned* p, unsigned v) {
  __hip_atomic_store(p, v, __ATOMIC_RELAXED, __HIP_MEMORY_SCOPE_AGENT);
}

// ---------------- convert f32 -> bf16 ----------------
__global__ void convert_bf16_kernel(const float* __restrict__ src, bf16* __restrict__ dst, int n4) {
  int i = blockIdx.x * 256 + threadIdx.x;
  if (i >= n4) return;
  float4 v = reinterpret_cast<const float4*>(src)[i];
  ushort4 o;
  o.x = (unsigned short)f2bs(v.x);
  o.y = (unsigned short)f2bs(v.y);
  o.z = (unsigned short)f2bs(v.z);
  o.w = (unsigned short)f2bs(v.w);
  reinterpret_cast<ushort4*>(dst)[i] = o;
}

// ---------------- embedding gather -> bf16 ----------------
__global__ void embed_kernel(const int* __restrict__ ids, const float* __restrict__ table,
                             bf16* __restrict__ x, int n4) {
  int i = blockIdx.x * 256 + threadIdx.x;
  if (i >= n4) return;
  int row = i >> 8;   // H/4 = 256 float4 per (b,t) row
  int c4 = i & 255;
  int tok = ids[row];
  float4 v = reinterpret_cast<const float4*>(table)[(size_t)tok * 256 + c4];
  ushort4 o;
  o.x = (unsigned short)f2bs(v.x);
  o.y = (unsigned short)f2bs(v.y);
  o.z = (unsigned short)f2bs(v.z);
  o.w = (unsigned short)f2bs(v.w);
  reinterpret_cast<ushort4*>(x)[i] = o;
}

// ---------------- xg = x @ W_ih^T + b_ih + b_hh ----------------
// LYR 0: A standard (m=b*256+t rows, K-major). LYR 1: A = ysT[(kg*16384+m)*8+e], m=t*64+b.
// W: (4096,1024) bf16 K-major. Epilogue writes xg in [q][g][m][8] order (full sectors).
#define BMX 128
#define BNX 128
#define BKX 64

template<int LYR>
__launch_bounds__(256, 2)
__global__ void gemm_xg_kernel(const bf16* __restrict__ A,
                               const bf16* __restrict__ W,
                               const float* __restrict__ bih,
                               const float* __restrict__ bhh,
                               bf16* __restrict__ xg) {
  __shared__ bf16 As[BMX][BKX + 8];
  __shared__ bf16 Bs[BNX][BKX + 8];
  const int n0 = blockIdx.x * BNX;
  const int m0 = blockIdx.y * BMX;
  const int tid = threadIdx.x;
  const int w = tid >> 6, l = tid & 63;
  const int wm = (w >> 1) * 64, wn = (w & 1) * 64;
  const int lr = l & 15, lk = (l >> 4) * 8;

  ffrag acc[4][4];
#pragma unroll
  for (int i = 0; i < 4; ++i)
#pragma unroll
    for (int j = 0; j < 4; ++j) acc[i][j] = ffrag{0.f, 0.f, 0.f, 0.f};

  const int sr = tid >> 1, sh = (tid & 1) * 32;
  for (int kb = 0; kb < HDIM; kb += BKX) {
    __syncthreads();
    {
      if (LYR == 0) {
        const uint4* ga = reinterpret_cast<const uint4*>(&A[(size_t)(m0 + sr) * HDIM + kb + sh]);
        uint4* la = reinterpret_cast<uint4*>(&As[sr][sh]);
        la[0] = ga[0]; la[1] = ga[1]; la[2] = ga[2]; la[3] = ga[3];
      } else {
        const int kg0 = (kb + sh) >> 3;
#pragma unroll
        for (int ii = 0; ii < 4; ++ii) {
          uint4 v = *reinterpret_cast<const uint4*>(&A[((size_t)(kg0 + ii) * 16384 + m0 + sr) * 8]);
          *reinterpret_cast<uint4*>(&As[sr][sh + ii * 8]) = v;
        }
      }
      const uint4* gb = reinterpret_cast<const uint4*>(&W[(size_t)(n0 + sr) * HDIM + kb + sh]);
      uint4* lb = reinterpret_cast<uint4*>(&Bs[sr][sh]);
      lb[0] = gb[0]; lb[1] = gb[1]; lb[2] = gb[2]; lb[3] = gb[3];
    }
    __syncthreads();
#pragma unroll
    for (int ks = 0; ks < 2; ++ks) {
      const int ko = ks * 32 + lk;
      bfrag af[4], bfv[4];
#pragma unroll
      for (int i = 0; i < 4; ++i)
        af[i] = *reinterpret_cast<const bfrag*>(&As[wm + i * 16 + lr][ko]);
#pragma unroll
      for (int j = 0; j < 4; ++j)
        bfv[j] = *reinterpret_cast<const bfrag*>(&Bs[wn + j * 16 + lr][ko]);
#pragma unroll
      for (int i = 0; i < 4; ++i)
#pragma unroll
        for (int j = 0; j < 4; ++j)
          acc[i][j] = mfma16(af[i], bfv[j], acc[i][j]);
    }
  }
  const int rg = (l >> 4) * 4;
#pragma unroll
  for (int j = 0; j < 4; ++j) {
    const int n = n0 + wn + j * 16 + lr;
    const float bias = bih[n] + bhh[n];
    const int q = n >> 10, g = (n & 1023) >> 3, jj = n & 7;
    bf16* base = xg + (size_t)(q * 128 + g) * 16384 * 8 + jj;
#pragma unroll
    for (int i = 0; i < 4; ++i) {
#pragma unroll
      for (int r = 0; r < 4; ++r) {
        const int m = m0 + wm + i * 16 + rg + r;   // == idx for this layer's xg order
        base[(size_t)m * 8] = f2b(acc[i][j][r] + bias);
      }
    }
  }
}

// ---------------- persistent LSTM recurrence ----------------
// 128 WGs x 512 threads (8 waves). Wave w: batch group bg=w>>1, K-half kh=w&1.
// W_hh fragments in registers; h in transposed half-split layout (dense lines);
// xg consumed at elementwise phase (cached loads, prefetched under the poll).
__launch_bounds__(512, 2)
__global__ void lstm_seq_kernel(const bf16* __restrict__ xg,
                                const bf16* __restrict__ Whh,  // (4096,1024) bf16
                                bf16* h0, bf16* h1,            // ping-pong hT
                                bf16* __restrict__ ysT,        // [g][t][b][8] or null
                                float* __restrict__ out_h,
                                float* __restrict__ out_c,
                                float* __restrict__ out_last,  // null except last layer
                                unsigned* __restrict__ flags,
                                int xbs, int xts) {
  __shared__ float gxp[2][BATCH][37];   // K-half partial gates (odd stride)
  const int wg = blockIdx.x;
  const int tid = threadIdx.x;
  const int w = tid >> 6, l = tid & 63;
  const int lr = l & 15, lkg = l >> 4;
  const int bg = w >> 1, kh = w & 1;
  const int kbase = kh * 512;
  const int j0 = wg * 8;

  // --- W_hh fragments into registers (once): 2 col-tiles x 16 k-steps ---
  bfrag breg0[16], breg1[16];
  {
    const int p0 = lr, p1 = 16 + lr;
    const size_t r0 = (size_t)((p0 >> 3) * HDIM + j0 + (p0 & 7)) * HDIM;
    const size_t r1 = (size_t)((p1 >> 3) * HDIM + j0 + (p1 & 7)) * HDIM;
#pragma unroll
    for (int ks = 0; ks < 16; ++ks) {
      breg0[ks] = *reinterpret_cast<const bfrag*>(&Whh[r0 + kbase + ks * 32 + lkg * 8]);
      breg1[ks] = *reinterpret_cast<const bfrag*>(&Whh[r1 + kbase + ks * 32 + lkg * 8]);
    }
  }

  const int eb = tid & 63;           // elementwise batch (tid<128)
  const int ej = (tid >> 6) * 4;     // col sub-offset: 0 (lo half) or 4 (hi half)
  float cc0 = 0.f, cc1 = 0.f, cc2 = 0.f, cc3 = 0.f;

  unsigned long long* hb0 = (unsigned long long*)h0;
  unsigned long long* hb1 = (unsigned long long*)h1;

  // init h0 slice (dense coalesced sc1 stores), then epoch-1 barrier
  if (tid < 128)
    store_u64_agent(&hb0[(size_t)(tid >> 6) * 8192 + wg * 64 + eb], 0ull);
  __builtin_amdgcn_s_waitcnt(0);
  if (tid == 0)  store_u32_agent(&flags[2 * wg], 1u);
  if (tid == 64) store_u32_agent(&flags[2 * wg + 1], 1u);
  if (tid < 128) {
    const unsigned long long* f2 = (const unsigned long long*)flags;
    for (;;) {
      unsigned long long v = load_u64_agent(&f2[tid]);
      if ((unsigned)v >= 1u && (unsigned)(v >> 32) >= 1u) break;
      __builtin_amdgcn_s_sleep(1);
    }
  }
  __syncthreads();
  __builtin_amdgcn_sched_barrier(0);

  // xg base for this WG; per-q offsets are QOFF apart
  const bf16* xgw = xg + (size_t)wg * 16384 * 8 + ej;
  unsigned long long xu0 = 0, xu1 = 0, xu2 = 0, xu3 = 0;
  if (tid < 128) {
    const size_t xo = (size_t)eb * xbs * 8;  // t = 0
    xu0 = *(const unsigned long long*)&xgw[xo];
    xu1 = *(const unsigned long long*)&xgw[QOFF + xo];
    xu2 = *(const unsigned long long*)&xgw[2 * QOFF + xo];
    xu3 = *(const unsigned long long*)&xgw[3 * QOFF + xo];
  }

  // per-lane h fragment base (u64 idx, lo half); lanes 0-15 consecutive => dense lines
  const size_t arow = (size_t)(kh * 64 + lkg) * 64 + 16 * bg + lr;

  for (int t = 0; t < TSTEPS; ++t) {
    const unsigned long long* hin = (t & 1) ? hb1 : hb0;
    unsigned long long*       hout = (t & 1) ? hb0 : hb1;
    ffrag a0 = ffrag{0.f, 0.f, 0.f, 0.f};
    ffrag a1 = ffrag{0.f, 0.f, 0.f, 0.f};
#pragma unroll
    for (int ks = 0; ks < 16; ++ks) {
      union { unsigned long long u[2]; bfrag f; } au;
      au.u[0] = load_u64_agent(&hin[arow + ks * 256]);
      au.u[1] = load_u64_agent(&hin[8192 + arow + ks * 256]);
      a0 = mfma16(au.f, breg0[ks], a0);
      a1 = mfma16(au.f, breg1[ks], a1);
    }
    {
      const int bx = 16 * bg + lkg * 4;
#pragma unroll
      for (int r = 0; r < 4; ++r) {
        gxp[kh][bx + r][lr]      = a0[r];
        gxp[kh][bx + r][16 + lr] = a1[r];
      }
    }
    __syncthreads();   // gxp ready
    if (tid < 128) {
      float hnew[4], cc[4] = {cc0, cc1, cc2, cc3};
      union { unsigned short s[4]; unsigned long long u; } pk;
#pragma unroll
      for (int m = 0; m < 4; ++m) {
        const int jc = ej + m;
        const float gi = gxp[0][eb][jc]      + gxp[1][eb][jc]      + bs2f((unsigned short)(xu0 >> (16 * m)));
        const float gf = gxp[0][eb][8 + jc]  + gxp[1][eb][8 + jc]  + bs2f((unsigned short)(xu1 >> (16 * m)));
        const float gg = gxp[0][eb][16 + jc] + gxp[1][eb][16 + jc] + bs2f((unsigned short)(xu2 >> (16 * m)));
        const float go = gxp[0][eb][24 + jc] + gxp[1][eb][24 + jc] + bs2f((unsigned short)(xu3 >> (16 * m)));
        const float iv = sigm(gi), fv = sigm(gf), gv = tanhfast(gg), ov = sigm(go);
        cc[m] = fv * cc[m] + iv * gv;
        hnew[m] = ov * tanhfast(cc[m]);
        pk.s[m] = (unsigned short)f2bs(hnew[m]);
      }
      cc0 = cc[0]; cc1 = cc[1]; cc2 = cc[2]; cc3 = cc[3];
      store_u64_agent(&hout[(size_t)(ej >> 2) * 8192 + wg * 64 + eb], pk.u);
      if (ysT)
        *(unsigned long long*)&ysT[(((size_t)wg * 256 + t) * 64 + eb) * 8 + ej] = pk.u;
      if (t == TSTEPS - 1) {
        float4 hv = {hnew[0], hnew[1], hnew[2], hnew[3]};
        float4 cv = {cc[0], cc[1], cc[2], cc[3]};
        *reinterpret_cast<float4*>(&out_h[(size_t)eb * HDIM + j0 + ej]) = hv;
        *reinterpret_cast<float4*>(&out_c[(size_t)eb * HDIM + j0 + ej]) = cv;
        if (out_last) *reinterpret_cast<float4*>(&out_last[(size_t)eb * HDIM + j0 + ej]) = hv;
      } else {
        __builtin_amdgcn_s_waitcnt(0);   // h stores acked at coherence point
        const unsigned ep = (unsigned)(t + 2);
        if (tid == 0)  store_u32_agent(&flags[2 * wg], ep);
        if (tid == 64) store_u32_agent(&flags[2 * wg + 1], ep);
        // prefetch next step's xg under the poll (cached loads, independent)
        const size_t xo = ((size_t)eb * xbs + (size_t)(t + 1) * xts) * 8;
        xu0 = *(const unsigned long long*)&xgw[xo];
        xu1 = *(const unsigned long long*)&xgw[QOFF + xo];
        xu2 = *(const unsigned long long*)&xgw[2 * QOFF + xo];
        xu3 = *(const unsigned long long*)&xgw[3 * QOFF + xo];
        const unsigned long long* f2 = (const unsigned long long*)flags;
        for (;;) {
          unsigned long long v = load_u64_agent(&f2[tid]);
          if ((unsigned)v >= ep && (unsigned)(v >> 32) >= ep) break;
          __builtin_amdgcn_s_sleep(1);
        }
      }
    }
    __syncthreads();
    __builtin_amdgcn_sched_barrier(0);
  }
}

// ---------------- logits = h_T @ W_proj^T + b_proj ----------------
// hfin is in transposed half-split hT layout.
__launch_bounds__(256, 2)
__global__ void logits_kernel(const bf16* __restrict__ hfin,
                              const float* __restrict__ Wp,   // (32000,1024) f32
                              const float* __restrict__ bp,
                              float* __restrict__ out) {      // (64,32000)
  const int tid = threadIdx.x;
  const int w = tid >> 6, l = tid & 63;
  const int lr = l & 15, lkg = l >> 4, lk = lkg * 8;
  const int col = blockIdx.x * 64 + w * 16 + lr;
  const float* wrow = &Wp[(size_t)col * HDIM];
  const unsigned long long* hb = (const unsigned long long*)hfin;
  ffrag acc[4];
#pragma unroll
  for (int i = 0; i < 4; ++i) acc[i] = ffrag{0.f, 0.f, 0.f, 0.f};
#pragma unroll 2
  for (int ks = 0; ks < 32; ++ks) {
    const int k = ks * 32 + lk;
    float4 wa = *reinterpret_cast<const float4*>(&wrow[k]);
    float4 wb = *reinterpret_cast<const float4*>(&wrow[k + 4]);
    bfrag bv;
    bv[0] = f2bs(wa.x); bv[1] = f2bs(wa.y); bv[2] = f2bs(wa.z); bv[3] = f2bs(wa.w);
    bv[4] = f2bs(wb.x); bv[5] = f2bs(wb.y); bv[6] = f2bs(wb.z); bv[7] = f2bs(wb.w);
    const size_t kg = (size_t)(ks * 4 + lkg);
#pragma unroll
    for (int i = 0; i < 4; ++i) {
      union { unsigned long long u[2]; bfrag f; } av;
      av.u[0] = hb[kg * 64 + i * 16 + lr];
      av.u[1] = hb[8192 + kg * 64 + i * 16 + lr];
      acc[i] = mfma16(av.f, bv, acc[i]);
    }
  }
  const float bias = bp[col];
#pragma unroll
  for (int i = 0; i < 4; ++i) {
#pragma unroll
    for (int r = 0; r < 4; ++r) {
      const int b = i * 16 + (l >> 4) * 4 + r;
      out[(size_t)b * VOCAB + col] = acc[i][r] + bias;
    }
  }
}

extern "C" void kernel_launch(void* const* d_in, const int* in_sizes, int n_in,
                              void* d_out, int out_size, void* d_ws, size_t ws_size,
                              hipStream_t stream) {
  const int*   ids   = (const int*)d_in[0];
  const float* table = (const float*)d_in[1];
  const float* Wih   = (const float*)d_in[2];
  const float* Whh   = (const float*)d_in[3];
  const float* bih   = (const float*)d_in[4];
  const float* bhh   = (const float*)d_in[5];
  const float* Wp    = (const float*)d_in[6];
  const float* bp    = (const float*)d_in[7];
  float* out = (float*)d_out;

  char* ws = (char*)d_ws;
  const size_t OFF_XG  = 0;                                              // 128 MB
  const size_t OFF_X   = OFF_XG  + (size_t)512 * 16384 * 8 * 2;          // xb / ysT (32 MB, aliased)
  const size_t OFF_WIH = OFF_X   + (size_t)BATCH * TSTEPS * HDIM * 2;
  const size_t OFF_WHH = OFF_WIH + (size_t)2 * GDIM * HDIM * 2;
  const size_t OFF_SYNC= OFF_WHH + (size_t)2 * GDIM * HDIM * 2;
  const size_t OFF_H0  = OFF_SYNC+ (size_t)65536;
  const size_t OFF_H1  = OFF_H0  + (size_t)BATCH * HDIM * 2;

  bf16* xg    = (bf16*)(ws + OFF_XG);
  bf16* xb    = (bf16*)(ws + OFF_X);    // embeddings (layer-1 A); reused as ysT after
  bf16* wihb  = (bf16*)(ws + OFF_WIH);
  bf16* whhb  = (bf16*)(ws + OFF_WHH);
  unsigned* sync = (unsigned*)(ws + OFF_SYNC);
  bf16* h0    = (bf16*)(ws + OFF_H0);
  bf16* h1    = (bf16*)(ws + OFF_H1);

  (void)hipMemsetAsync(sync, 0, 65536, stream);

  const int nconv4 = 2 * GDIM * HDIM / 4;
  convert_bf16_kernel<<<nconv4 / 256, 256, 0, stream>>>(Wih, wihb, nconv4);
  convert_bf16_kernel<<<nconv4 / 256, 256, 0, stream>>>(Whh, whhb, nconv4);
  const int nemb4 = BATCH * TSTEPS * HDIM / 4;
  embed_kernel<<<nemb4 / 256, 256, 0, stream>>>(ids, table, xb, nemb4);

  float* out_last   = out;              // (64,1024)
  float* out_logits = out + 65536;      // (64,32000)
  float* out_hn     = out + 2113536;    // (2,64,1024)
  float* out_cn     = out + 2244608;    // (2,64,1024)

  // ---- layer 1 ----
  gemm_xg_kernel<0><<<dim3(GDIM / BNX, (BATCH * TSTEPS) / BMX), 256, 0, stream>>>(
      xb, wihb, bih, bhh, xg);
  lstm_seq_kernel<<<NWG_SEQ, 512, 0, stream>>>(
      xg, whhb, h0, h1, xb /* ysT overwrites embeddings */,
      out_hn, out_cn, nullptr, sync, 256, 1);

  // ---- layer 2 ----
  gemm_xg_kernel<1><<<dim3(GDIM / BNX, (BATCH * TSTEPS) / BMX), 256, 0, stream>>>(
      xb /* ysT */, wihb + (size_t)GDIM * HDIM, bih + GDIM, bhh + GDIM, xg);
  lstm_seq_kernel<<<NWG_SEQ, 512, 0, stream>>>(
      xg, whhb + (size_t)GDIM * HDIM, h0, h1, nullptr,
      out_hn + (size_t)BATCH * HDIM, out_cn + (size_t)BATCH * HDIM,
      out_last, sync + 512, 1, 64);

  logits_kernel<<<VOCAB / 64, 256, 0, stream>>>(h0, Wp, bp, out_logits);
}

// Round 7
// 3554.378 us; speedup vs baseline: 2.0846x; 1.0088x over previous
//
#include <hip/hip_runtime.h>
#include <hip/hip_bf16.h>
#include <stdint.h>
#include <stddef.h>

typedef __hip_bfloat16 bf16;
typedef __attribute__((ext_vector_type(8))) short bfrag;
typedef __attribute__((ext_vector_type(4))) float ffrag;

#define HDIM 1024
#define BATCH 64
#define TSTEPS 256
#define GDIM 4096
#define VOCAB 32000
#define NWG_SEQ 128   // 128 WGs x 512 threads; WG g owns hidden cols 8g..8g+7

// xg element layout: ((q*128 + g)*16384 + idx)*8 + jj   (q=gate, g=WG, jj=col&7)
//   layer 1: idx = b*256 + t ; layer 2: idx = t*64 + b  (matches gemm m-order)
#define QOFF ((size_t)128 * 16384 * 8)
// h-history: 257 slots x 128 KB; slot t = h INPUT to step t (write-once).
// within slot (u64 units): half*8192 + kg*64 + b   (half=(col&7)>>2, kg=col>>3)
#define HSLOT 16384ull   // u64 per slot

__device__ __forceinline__ float b2f(bf16 x) { return __bfloat162float(x); }
__device__ __forceinline__ bf16 f2b(float x) { return __float2bfloat16(x); }
__device__ __forceinline__ short f2bs(float x) {
  bf16 b = __float2bfloat16(x);
  return *reinterpret_cast<short*>(&b);
}
__device__ __forceinline__ float bs2f(unsigned short u) {
  union { unsigned int i; float f; } v;
  v.i = ((unsigned int)u) << 16;
  return v.f;
}
__device__ __forceinline__ ffrag mfma16(bfrag a, bfrag b, ffrag c) {
  return __builtin_amdgcn_mfma_f32_16x16x32_bf16(a, b, c, 0, 0, 0);
}
__device__ __forceinline__ float sigm(float x) { return 1.0f / (1.0f + __expf(-x)); }
__device__ __forceinline__ float tanhfast(float x) {
  float e = __expf(2.0f * x);
  return 1.0f - 2.0f / (e + 1.0f);
}

// agent-scope point-coherent ops (write-through to MALL / bypass stale caches)
__device__ __forceinline__ void store_u64_agent(unsigned long long* p, unsigned long long v) {
  __hip_atomic_store(p, v, __ATOMIC_RELAXED, __HIP_MEMORY_SCOPE_AGENT);
}
__device__ __forceinline__ unsigned long long load_u64_agent(const unsigned long long* p) {
  return __hip_atomic_load(p, __ATOMIC_RELAXED, __HIP_MEMORY_SCOPE_AGENT);
}
__device__ __forceinline__ void store_u32_agent(unsigned* p, unsigned v) {
  __hip_atomic_store(p, v, __ATOMIC_RELAXED, __HIP_MEMORY_SCOPE_AGENT);
}

// ---------------- convert f32 -> bf16 ----------------
__global__ void convert_bf16_kernel(const float* __restrict__ src, bf16* __restrict__ dst, int n4) {
  int i = blockIdx.x * 256 + threadIdx.x;
  if (i >= n4) return;
  float4 v = reinterpret_cast<const float4*>(src)[i];
  ushort4 o;
  o.x = (unsigned short)f2bs(v.x);
  o.y = (unsigned short)f2bs(v.y);
  o.z = (unsigned short)f2bs(v.z);
  o.w = (unsigned short)f2bs(v.w);
  reinterpret_cast<ushort4*>(dst)[i] = o;
}

// ---------------- embedding gather -> bf16 ----------------
__global__ void embed_kernel(const int* __restrict__ ids, const float* __restrict__ table,
                             bf16* __restrict__ x, int n4) {
  int i = blockIdx.x * 256 + threadIdx.x;
  if (i >= n4) return;
  int row = i >> 8;   // H/4 = 256 float4 per (b,t) row
  int c4 = i & 255;
  int tok = ids[row];
  float4 v = reinterpret_cast<const float4*>(table)[(size_t)tok * 256 + c4];
  ushort4 o;
  o.x = (unsigned short)f2bs(v.x);
  o.y = (unsigned short)f2bs(v.y);
  o.z = (unsigned short)f2bs(v.z);
  o.w = (unsigned short)f2bs(v.w);
  reinterpret_cast<ushort4*>(x)[i] = o;
}

// ---------------- xg = x @ W_ih^T + b_ih + b_hh ----------------
// LYR 0: A standard (m=b*256+t rows, K-major).
// LYR 1: A = h-history (write-once); row m=t*64+b comes from slot (t+1).
#define BMX 128
#define BNX 128
#define BKX 64

template<int LYR>
__launch_bounds__(256, 2)
__global__ void gemm_xg_kernel(const bf16* __restrict__ A,
                               const bf16* __restrict__ W,
                               const float* __restrict__ bih,
                               const float* __restrict__ bhh,
                               bf16* __restrict__ xg) {
  __shared__ bf16 As[BMX][BKX + 8];
  __shared__ bf16 Bs[BNX][BKX + 8];
  const int n0 = blockIdx.x * BNX;
  const int m0 = blockIdx.y * BMX;
  const int tid = threadIdx.x;
  const int w = tid >> 6, l = tid & 63;
  const int wm = (w >> 1) * 64, wn = (w & 1) * 64;
  const int lr = l & 15, lk = (l >> 4) * 8;

  ffrag acc[4][4];
#pragma unroll
  for (int i = 0; i < 4; ++i)
#pragma unroll
    for (int j = 0; j < 4; ++j) acc[i][j] = ffrag{0.f, 0.f, 0.f, 0.f};

  const int sr = tid >> 1, sh = (tid & 1) * 32;
  for (int kb = 0; kb < HDIM; kb += BKX) {
    __syncthreads();
    {
      if (LYR == 0) {
        const uint4* ga = reinterpret_cast<const uint4*>(&A[(size_t)(m0 + sr) * HDIM + kb + sh]);
        uint4* la = reinterpret_cast<uint4*>(&As[sr][sh]);
        la[0] = ga[0]; la[1] = ga[1]; la[2] = ga[2]; la[3] = ga[3];
      } else {
        const unsigned long long* hb = (const unsigned long long*)A;
        const int m = m0 + sr;                    // t = m>>6, b = m&63
        const size_t tb = (size_t)((m >> 6) + 1) * HSLOT + (m & 63);
        const int kg0 = (kb + sh) >> 3;
#pragma unroll
        for (int ii = 0; ii < 4; ++ii) {
          unsigned long long lo = hb[tb + (size_t)(kg0 + ii) * 64];
          unsigned long long hi = hb[tb + 8192 + (size_t)(kg0 + ii) * 64];
          *(unsigned long long*)&As[sr][sh + ii * 8]     = lo;
          *(unsigned long long*)&As[sr][sh + ii * 8 + 4] = hi;
        }
      }
      const uint4* gb = reinterpret_cast<const uint4*>(&W[(size_t)(n0 + sr) * HDIM + kb + sh]);
      uint4* lb = reinterpret_cast<uint4*>(&Bs[sr][sh]);
      lb[0] = gb[0]; lb[1] = gb[1]; lb[2] = gb[2]; lb[3] = gb[3];
    }
    __syncthreads();
#pragma unroll
    for (int ks = 0; ks < 2; ++ks) {
      const int ko = ks * 32 + lk;
      bfrag af[4], bfv[4];
#pragma unroll
      for (int i = 0; i < 4; ++i)
        af[i] = *reinterpret_cast<const bfrag*>(&As[wm + i * 16 + lr][ko]);
#pragma unroll
      for (int j = 0; j < 4; ++j)
        bfv[j] = *reinterpret_cast<const bfrag*>(&Bs[wn + j * 16 + lr][ko]);
#pragma unroll
      for (int i = 0; i < 4; ++i)
#pragma unroll
        for (int j = 0; j < 4; ++j)
          acc[i][j] = mfma16(af[i], bfv[j], acc[i][j]);
    }
  }
  const int rg = (l >> 4) * 4;
#pragma unroll
  for (int j = 0; j < 4; ++j) {
    const int n = n0 + wn + j * 16 + lr;
    const float bias = bih[n] + bhh[n];
    const int q = n >> 10, g = (n & 1023) >> 3, jj = n & 7;
    bf16* base = xg + (size_t)(q * 128 + g) * 16384 * 8 + jj;
#pragma unroll
    for (int i = 0; i < 4; ++i) {
#pragma unroll
      for (int r = 0; r < 4; ++r) {
        const int m = m0 + wm + i * 16 + rg + r;   // == idx for this layer's xg order
        base[(size_t)m * 8] = f2b(acc[i][j][r] + bias);
      }
    }
  }
}

// ---------------- persistent LSTM recurrence ----------------
// 128 WGs x 512 threads (8 waves). Wave w: batch group bg=w>>1, K-half kh=w&1.
// W_hh fragments in registers. h in a write-once rotating history: producers
// store sc1 (visible at MALL); consumers use PLAIN CACHED loads -- no address
// is ever rewritten within the dispatch, so cached copies are always correct,
// and each XCD's L2 serves 15 of 16 WGs' reads.
__launch_bounds__(512, 2)
__global__ void lstm_seq_kernel(const bf16* __restrict__ xg,
                                const bf16* __restrict__ Whh,  // (4096,1024) bf16
                                bf16* hist,                    // 257 x 128 KB slots
                                float* __restrict__ out_h,
                                float* __restrict__ out_c,
                                float* __restrict__ out_last,  // null except last layer
                                unsigned* __restrict__ flags,
                                int xbs, int xts) {
  __shared__ float gxp[2][BATCH][37];   // K-half partial gates (odd stride)
  const int wg = blockIdx.x;
  const int tid = threadIdx.x;
  const int w = tid >> 6, l = tid & 63;
  const int lr = l & 15, lkg = l >> 4;
  const int bg = w >> 1, kh = w & 1;
  const int kbase = kh * 512;
  const int j0 = wg * 8;

  // --- W_hh fragments into registers (once): 2 col-tiles x 16 k-steps ---
  bfrag breg0[16], breg1[16];
  {
    const int p0 = lr, p1 = 16 + lr;
    const size_t r0 = (size_t)((p0 >> 3) * HDIM + j0 + (p0 & 7)) * HDIM;
    const size_t r1 = (size_t)((p1 >> 3) * HDIM + j0 + (p1 & 7)) * HDIM;
#pragma unroll
    for (int ks = 0; ks < 16; ++ks) {
      breg0[ks] = *reinterpret_cast<const bfrag*>(&Whh[r0 + kbase + ks * 32 + lkg * 8]);
      breg1[ks] = *reinterpret_cast<const bfrag*>(&Whh[r1 + kbase + ks * 32 + lkg * 8]);
    }
  }

  const int eb = tid & 63;           // elementwise batch (tid<128)
  const int ej = (tid >> 6) * 4;     // col sub-offset: 0 (lo half) or 4 (hi half)
  float cc0 = 0.f, cc1 = 0.f, cc2 = 0.f, cc3 = 0.f;

  unsigned long long* hb = (unsigned long long*)hist;

  // init slot 0 (zeros, sc1), then epoch-1 barrier
  if (tid < 128)
    store_u64_agent(&hb[(size_t)(tid >> 6) * 8192 + wg * 64 + eb], 0ull);
  __builtin_amdgcn_s_waitcnt(0);
  if (tid == 0)  store_u32_agent(&flags[2 * wg], 1u);
  if (tid == 64) store_u32_agent(&flags[2 * wg + 1], 1u);
  if (tid < 128) {
    const unsigned long long* f2 = (const unsigned long long*)flags;
    for (;;) {
      unsigned long long v = load_u64_agent(&f2[tid]);
      if ((unsigned)v >= 1u && (unsigned)(v >> 32) >= 1u) break;
      __builtin_amdgcn_s_sleep(1);
    }
  }
  __syncthreads();
  __builtin_amdgcn_sched_barrier(0);

  // xg base for this WG; per-q offsets are QOFF apart
  const bf16* xgw = xg + (size_t)wg * 16384 * 8 + ej;
  unsigned long long xu0 = 0, xu1 = 0, xu2 = 0, xu3 = 0;
  if (tid < 128) {
    const size_t xo = (size_t)eb * xbs * 8;  // t = 0
    xu0 = *(const unsigned long long*)&xgw[xo];
    xu1 = *(const unsigned long long*)&xgw[QOFF + xo];
    xu2 = *(const unsigned long long*)&xgw[2 * QOFF + xo];
    xu3 = *(const unsigned long long*)&xgw[3 * QOFF + xo];
  }

  // per-lane h fragment base (u64 idx, lo half); lanes 0-15 consecutive => dense lines
  const size_t arow = (size_t)(kh * 64 + lkg) * 64 + 16 * bg + lr;

  for (int t = 0; t < TSTEPS; ++t) {
    const unsigned long long* hin = hb + (size_t)t * HSLOT;
    ffrag a0 = ffrag{0.f, 0.f, 0.f, 0.f};
    ffrag a1 = ffrag{0.f, 0.f, 0.f, 0.f};
#pragma unroll
    for (int ks = 0; ks < 16; ++ks) {
      union { unsigned long long u[2]; bfrag f; } au;
      au.u[0] = hin[arow + ks * 256];          // plain cached loads (write-once data)
      au.u[1] = hin[8192 + arow + ks * 256];
      a0 = mfma16(au.f, breg0[ks], a0);
      a1 = mfma16(au.f, breg1[ks], a1);
    }
    {
      const int bx = 16 * bg + lkg * 4;
#pragma unroll
      for (int r = 0; r < 4; ++r) {
        gxp[kh][bx + r][lr]      = a0[r];
        gxp[kh][bx + r][16 + lr] = a1[r];
      }
    }
    __syncthreads();   // gxp ready
    if (tid < 128) {
      float hnew[4], cc[4] = {cc0, cc1, cc2, cc3};
      union { unsigned short s[4]; unsigned long long u; } pk;
#pragma unroll
      for (int m = 0; m < 4; ++m) {
        const int jc = ej + m;
        const float gi = gxp[0][eb][jc]      + gxp[1][eb][jc]      + bs2f((unsigned short)(xu0 >> (16 * m)));
        const float gf = gxp[0][eb][8 + jc]  + gxp[1][eb][8 + jc]  + bs2f((unsigned short)(xu1 >> (16 * m)));
        const float gg = gxp[0][eb][16 + jc] + gxp[1][eb][16 + jc] + bs2f((unsigned short)(xu2 >> (16 * m)));
        const float go = gxp[0][eb][24 + jc] + gxp[1][eb][24 + jc] + bs2f((unsigned short)(xu3 >> (16 * m)));
        const float iv = sigm(gi), fv = sigm(gf), gv = tanhfast(gg), ov = sigm(go);
        cc[m] = fv * cc[m] + iv * gv;
        hnew[m] = ov * tanhfast(cc[m]);
        pk.s[m] = (unsigned short)f2bs(hnew[m]);
      }
      cc0 = cc[0]; cc1 = cc[1]; cc2 = cc[2]; cc3 = cc[3];
      // h(t+1) -> fresh slot (sc1: visible at MALL before flag release)
      store_u64_agent(&hb[(size_t)(t + 1) * HSLOT + (size_t)(ej >> 2) * 8192 + wg * 64 + eb], pk.u);
      if (t == TSTEPS - 1) {
        float4 hv = {hnew[0], hnew[1], hnew[2], hnew[3]};
        float4 cv = {cc[0], cc[1], cc[2], cc[3]};
        *reinterpret_cast<float4*>(&out_h[(size_t)eb * HDIM + j0 + ej]) = hv;
        *reinterpret_cast<float4*>(&out_c[(size_t)eb * HDIM + j0 + ej]) = cv;
        if (out_last) *reinterpret_cast<float4*>(&out_last[(size_t)eb * HDIM + j0 + ej]) = hv;
      } else {
        __builtin_amdgcn_s_waitcnt(0);   // h stores acked at coherence point
        const unsigned ep = (unsigned)(t + 2);
        if (tid == 0)  store_u32_agent(&flags[2 * wg], ep);
        if (tid == 64) store_u32_agent(&flags[2 * wg + 1], ep);
        // prefetch next step's xg under the poll (cached loads, independent)
        const size_t xo = ((size_t)eb * xbs + (size_t)(t + 1) * xts) * 8;
        xu0 = *(const unsigned long long*)&xgw[xo];
        xu1 = *(const unsigned long long*)&xgw[QOFF + xo];
        xu2 = *(const unsigned long long*)&xgw[2 * QOFF + xo];
        xu3 = *(const unsigned long long*)&xgw[3 * QOFF + xo];
        const unsigned long long* f2 = (const unsigned long long*)flags;
        for (;;) {
          unsigned long long v = load_u64_agent(&f2[tid]);
          if ((unsigned)v >= ep && (unsigned)(v >> 32) >= ep) break;
          __builtin_amdgcn_s_sleep(1);
        }
      }
    }
    __syncthreads();
    __builtin_amdgcn_sched_barrier(0);
  }
}

// ---------------- logits = h_T @ W_proj^T + b_proj ----------------
// hfin points at the final h slot (half-split hT layout).
__launch_bounds__(256, 2)
__global__ void logits_kernel(const bf16* __restrict__ hfin,
                              const float* __restrict__ Wp,   // (32000,1024) f32
                              const float* __restrict__ bp,
                              float* __restrict__ out) {      // (64,32000)
  const int tid = threadIdx.x;
  const int w = tid >> 6, l = tid & 63;
  const int lr = l & 15, lkg = l >> 4, lk = lkg * 8;
  const int col = blockIdx.x * 64 + w * 16 + lr;
  const float* wrow = &Wp[(size_t)col * HDIM];
  const unsigned long long* hb = (const unsigned long long*)hfin;
  ffrag acc[4];
#pragma unroll
  for (int i = 0; i < 4; ++i) acc[i] = ffrag{0.f, 0.f, 0.f, 0.f};
#pragma unroll 2
  for (int ks = 0; ks < 32; ++ks) {
    const int k = ks * 32 + lk;
    float4 wa = *reinterpret_cast<const float4*>(&wrow[k]);
    float4 wb = *reinterpret_cast<const float4*>(&wrow[k + 4]);
    bfrag bv;
    bv[0] = f2bs(wa.x); bv[1] = f2bs(wa.y); bv[2] = f2bs(wa.z); bv[3] = f2bs(wa.w);
    bv[4] = f2bs(wb.x); bv[5] = f2bs(wb.y); bv[6] = f2bs(wb.z); bv[7] = f2bs(wb.w);
    const size_t kg = (size_t)(ks * 4 + lkg);
#pragma unroll
    for (int i = 0; i < 4; ++i) {
      union { unsigned long long u[2]; bfrag f; } av;
      av.u[0] = hb[kg * 64 + i * 16 + lr];
      av.u[1] = hb[8192 + kg * 64 + i * 16 + lr];
      acc[i] = mfma16(av.f, bv, acc[i]);
    }
  }
  const float bias = bp[col];
#pragma unroll
  for (int i = 0; i < 4; ++i) {
#pragma unroll
    for (int r = 0; r < 4; ++r) {
      const int b = i * 16 + (l >> 4) * 4 + r;
      out[(size_t)b * VOCAB + col] = acc[i][r] + bias;
    }
  }
}

extern "C" void kernel_launch(void* const* d_in, const int* in_sizes, int n_in,
                              void* d_out, int out_size, void* d_ws, size_t ws_size,
                              hipStream_t stream) {
  const int*   ids   = (const int*)d_in[0];
  const float* table = (const float*)d_in[1];
  const float* Wih   = (const float*)d_in[2];
  const float* Whh   = (const float*)d_in[3];
  const float* bih   = (const float*)d_in[4];
  const float* bhh   = (const float*)d_in[5];
  const float* Wp    = (const float*)d_in[6];
  const float* bp    = (const float*)d_in[7];
  float* out = (float*)d_out;

  char* ws = (char*)d_ws;
  const size_t HISTB = 257ull * 131072ull;                    // 33,685,504
  const size_t OFF_XG  = 0;                                   // 134,217,728
  const size_t OFF_X   = OFF_XG + (size_t)512 * 16384 * 8 * 2;// xb (32 MB) & hist0 alias
  const size_t OFF_WIH = OFF_X + HISTB;
  const size_t OFF_WHH = OFF_WIH + (size_t)2 * GDIM * HDIM * 2;
  const size_t OFF_SYNC= OFF_WHH + (size_t)2 * GDIM * HDIM * 2;
  const size_t OFF_H1  = OFF_SYNC + (size_t)65536;            // hist1

  bf16* xg    = (bf16*)(ws + OFF_XG);
  bf16* xb    = (bf16*)(ws + OFF_X);    // embeddings; reused as hist0 after gemm<0>
  bf16* wihb  = (bf16*)(ws + OFF_WIH);
  bf16* whhb  = (bf16*)(ws + OFF_WHH);
  unsigned* sync = (unsigned*)(ws + OFF_SYNC);
  bf16* hist1 = (bf16*)(ws + OFF_H1);

  (void)hipMemsetAsync(sync, 0, 65536, stream);

  const int nconv4 = 2 * GDIM * HDIM / 4;
  convert_bf16_kernel<<<nconv4 / 256, 256, 0, stream>>>(Wih, wihb, nconv4);
  convert_bf16_kernel<<<nconv4 / 256, 256, 0, stream>>>(Whh, whhb, nconv4);
  const int nemb4 = BATCH * TSTEPS * HDIM / 4;
  embed_kernel<<<nemb4 / 256, 256, 0, stream>>>(ids, table, xb, nemb4);

  float* out_last   = out;              // (64,1024)
  float* out_logits = out + 65536;      // (64,32000)
  float* out_hn     = out + 2113536;    // (2,64,1024)
  float* out_cn     = out + 2244608;    // (2,64,1024)

  // ---- layer 1 ----
  gemm_xg_kernel<0><<<dim3(GDIM / BNX, (BATCH * TSTEPS) / BMX), 256, 0, stream>>>(
      xb, wihb, bih, bhh, xg);
  lstm_seq_kernel<<<NWG_SEQ, 512, 0, stream>>>(
      xg, whhb, xb /* hist0 overwrites embeddings */,
      out_hn, out_cn, nullptr, sync, 256, 1);

  // ---- layer 2 ----
  gemm_xg_kernel<1><<<dim3(GDIM / BNX, (BATCH * TSTEPS) / BMX), 256, 0, stream>>>(
      xb /* hist0 */, wihb + (size_t)GDIM * HDIM, bih + GDIM, bhh + GDIM, xg);
  lstm_seq_kernel<<<NWG_SEQ, 512, 0, stream>>>(
      xg, whhb + (size_t)GDIM * HDIM, hist1,
      out_hn + (size_t)BATCH * HDIM, out_cn + (size_t)BATCH * HDIM,
      out_last, sync + 512, 1, 64);

  logits_kernel<<<VOCAB / 64, 256, 0, stream>>>(
      (const bf16*)((char*)hist1 + 256ull * 131072ull), Wp, bp, out_logits);
}

// Round 8
// 2315.237 us; speedup vs baseline: 3.2003x; 1.5352x over previous
//
#include <hip/hip_runtime.h>
#include <hip/hip_bf16.h>
#include <stdint.h>
#include <stddef.h>

typedef __hip_bfloat16 bf16;
typedef __attribute__((ext_vector_type(8))) short bfrag;
typedef __attribute__((ext_vector_type(4))) float ffrag;

#define HDIM 1024
#define BATCH 64
#define TSTEPS 256
#define GDIM 4096
#define VOCAB 32000

// xg element layout: ((q*128 + cg)*16384 + idx)*8 + jj   (q=gate, cg=col octet, jj=col&7)
//   layer 1: idx = b*256 + t ; layer 2: idx = t*64 + b  (matches gemm m-order)
// h-history: 257 slots x 128 KB; slot (256 - t) = h INPUT to step t (descending => no
// prefetch-ahead hazard). within slot (u64 units): half*8192 + kg*64 + b.
#define HSLOT 16384ull   // u64 per slot

__device__ __forceinline__ float b2f(bf16 x) { return __bfloat162float(x); }
__device__ __forceinline__ bf16 f2b(float x) { return __float2bfloat16(x); }
__device__ __forceinline__ short f2bs(float x) {
  bf16 b = __float2bfloat16(x);
  return *reinterpret_cast<short*>(&b);
}
__device__ __forceinline__ float bs2f(unsigned short u) {
  union { unsigned int i; float f; } v;
  v.i = ((unsigned int)u) << 16;
  return v.f;
}
__device__ __forceinline__ ffrag mfma16(bfrag a, bfrag b, ffrag c) {
  return __builtin_amdgcn_mfma_f32_16x16x32_bf16(a, b, c, 0, 0, 0);
}
__device__ __forceinline__ float sigm(float x) { return 1.0f / (1.0f + __expf(-x)); }
__device__ __forceinline__ float tanhfast(float x) {
  float e = __expf(2.0f * x);
  return 1.0f - 2.0f / (e + 1.0f);
}

// agent-scope point-coherent ops (write-through to MALL / bypass stale caches)
__device__ __forceinline__ void store_u16_agent(unsigned short* p, unsigned short v) {
  __hip_atomic_store(p, v, __ATOMIC_RELAXED, __HIP_MEMORY_SCOPE_AGENT);
}
__device__ __forceinline__ unsigned long long load_u64_agent(const unsigned long long* p) {
  return __hip_atomic_load(p, __ATOMIC_RELAXED, __HIP_MEMORY_SCOPE_AGENT);
}
__device__ __forceinline__ void store_u32_agent(unsigned* p, unsigned v) {
  __hip_atomic_store(p, v, __ATOMIC_RELAXED, __HIP_MEMORY_SCOPE_AGENT);
}

// ---------------- convert f32 -> bf16 ----------------
__global__ void convert_bf16_kernel(const float* __restrict__ src, bf16* __restrict__ dst, int n4) {
  int i = blockIdx.x * 256 + threadIdx.x;
  if (i >= n4) return;
  float4 v = reinterpret_cast<const float4*>(src)[i];
  ushort4 o;
  o.x = (unsigned short)f2bs(v.x);
  o.y = (unsigned short)f2bs(v.y);
  o.z = (unsigned short)f2bs(v.z);
  o.w = (unsigned short)f2bs(v.w);
  reinterpret_cast<ushort4*>(dst)[i] = o;
}

// ---------------- embedding gather -> bf16 ----------------
__global__ void embed_kernel(const int* __restrict__ ids, const float* __restrict__ table,
                             bf16* __restrict__ x, int n4) {
  int i = blockIdx.x * 256 + threadIdx.x;
  if (i >= n4) return;
  int row = i >> 8;
  int c4 = i & 255;
  int tok = ids[row];
  float4 v = reinterpret_cast<const float4*>(table)[(size_t)tok * 256 + c4];
  ushort4 o;
  o.x = (unsigned short)f2bs(v.x);
  o.y = (unsigned short)f2bs(v.y);
  o.z = (unsigned short)f2bs(v.z);
  o.w = (unsigned short)f2bs(v.w);
  reinterpret_cast<ushort4*>(x)[i] = o;
}

// ---------------- xg = x @ W_ih^T + b_ih + b_hh ----------------
#define BMX 128
#define BNX 128
#define BKX 64

template<int LYR>
__launch_bounds__(256, 2)
__global__ void gemm_xg_kernel(const bf16* __restrict__ A,
                               const bf16* __restrict__ W,
                               const float* __restrict__ bih,
                               const float* __restrict__ bhh,
                               bf16* __restrict__ xg) {
  __shared__ bf16 As[BMX][BKX + 8];
  __shared__ bf16 Bs[BNX][BKX + 8];
  const int n0 = blockIdx.x * BNX;
  const int m0 = blockIdx.y * BMX;
  const int tid = threadIdx.x;
  const int w = tid >> 6, l = tid & 63;
  const int wm = (w >> 1) * 64, wn = (w & 1) * 64;
  const int lr = l & 15, lk = (l >> 4) * 8;

  ffrag acc[4][4];
#pragma unroll
  for (int i = 0; i < 4; ++i)
#pragma unroll
    for (int j = 0; j < 4; ++j) acc[i][j] = ffrag{0.f, 0.f, 0.f, 0.f};

  const int sr = tid >> 1, sh = (tid & 1) * 32;
  for (int kb = 0; kb < HDIM; kb += BKX) {
    __syncthreads();
    {
      if (LYR == 0) {
        const uint4* ga = reinterpret_cast<const uint4*>(&A[(size_t)(m0 + sr) * HDIM + kb + sh]);
        uint4* la = reinterpret_cast<uint4*>(&As[sr][sh]);
        la[0] = ga[0]; la[1] = ga[1]; la[2] = ga[2]; la[3] = ga[3];
      } else {
        const unsigned long long* hb = (const unsigned long long*)A;
        const int m = m0 + sr;                    // t = m>>6, b = m&63
        const size_t tb = (size_t)(255 - (m >> 6)) * HSLOT + (m & 63);
        const int kg0 = (kb + sh) >> 3;
#pragma unroll
        for (int ii = 0; ii < 4; ++ii) {
          unsigned long long lo = hb[tb + (size_t)(kg0 + ii) * 64];
          unsigned long long hi = hb[tb + 8192 + (size_t)(kg0 + ii) * 64];
          *(unsigned long long*)&As[sr][sh + ii * 8]     = lo;
          *(unsigned long long*)&As[sr][sh + ii * 8 + 4] = hi;
        }
      }
      const uint4* gb = reinterpret_cast<const uint4*>(&W[(size_t)(n0 + sr) * HDIM + kb + sh]);
      uint4* lb = reinterpret_cast<uint4*>(&Bs[sr][sh]);
      lb[0] = gb[0]; lb[1] = gb[1]; lb[2] = gb[2]; lb[3] = gb[3];
    }
    __syncthreads();
#pragma unroll
    for (int ks = 0; ks < 2; ++ks) {
      const int ko = ks * 32 + lk;
      bfrag af[4], bfv[4];
#pragma unroll
      for (int i = 0; i < 4; ++i)
        af[i] = *reinterpret_cast<const bfrag*>(&As[wm + i * 16 + lr][ko]);
#pragma unroll
      for (int j = 0; j < 4; ++j)
        bfv[j] = *reinterpret_cast<const bfrag*>(&Bs[wn + j * 16 + lr][ko]);
#pragma unroll
      for (int i = 0; i < 4; ++i)
#pragma unroll
        for (int j = 0; j < 4; ++j)
          acc[i][j] = mfma16(af[i], bfv[j], acc[i][j]);
    }
  }
  const int rg = (l >> 4) * 4;
#pragma unroll
  for (int j = 0; j < 4; ++j) {
    const int n = n0 + wn + j * 16 + lr;
    const float bias = bih[n] + bhh[n];
    const int q = n >> 10, g = (n & 1023) >> 3, jj = n & 7;
    bf16* base = xg + (size_t)(q * 128 + g) * 16384 * 8 + jj;
#pragma unroll
    for (int i = 0; i < 4; ++i) {
#pragma unroll
      for (int r = 0; r < 4; ++r) {
        const int m = m0 + wm + i * 16 + rg + r;
        base[(size_t)m * 8] = f2b(acc[i][j][r] + bias);
      }
    }
  }
}

// ---------------- persistent LSTM recurrence ----------------
// 512 WGs x 128 threads (2 waves). WG (bg = id&3, cg = id>>2) owns rows
// 16bg..16bg+15 x hidden cols 8cg..8cg+7. Wave w = K-half. Per-WAVE flags;
// consumer polls only its own bg's 256 flags (batch groups drift freely).
// The sibling-wave flag doubles as the intra-WG dependency (no 2nd barrier).
__launch_bounds__(128, 1)
__global__ void lstm_seq_kernel(const bf16* __restrict__ xg,
                                const bf16* __restrict__ Whh,  // (4096,1024) bf16
                                bf16* hist,                    // 257 x 128 KB slots
                                float* __restrict__ out_h,
                                float* __restrict__ out_c,
                                float* __restrict__ out_last,  // null except last layer
                                unsigned* __restrict__ flags,  // u32[4][128][2]
                                int xbs, int xts) {
  __shared__ float gxp[2][16][33];
  const int wgid = blockIdx.x;
  const int bg = wgid & 3, cg = wgid >> 2;
  const int tid = threadIdx.x;
  const int w = tid >> 6, l = tid & 63;
  const int lr = l & 15, lkg = l >> 4;
  const int kh = w, kbase = kh * 512;

  // --- W_hh fragments into registers (once): 2 col-sets x 16 k-steps ---
  bfrag breg0[16], breg1[16];
  {
    const int q = lr >> 2, ja = lr & 3;
    const size_t g0 = ((size_t)q * HDIM + cg * 8 + ja) * HDIM + kbase + lkg * 8;
    const size_t g1 = ((size_t)q * HDIM + cg * 8 + 4 + ja) * HDIM + kbase + lkg * 8;
#pragma unroll
    for (int ks = 0; ks < 16; ++ks) {
      breg0[ks] = *reinterpret_cast<const bfrag*>(&Whh[g0 + ks * 32]);
      breg1[ks] = *reinterpret_cast<const bfrag*>(&Whh[g1 + ks * 32]);
    }
  }

  // elementwise identity: thread -> (b, j)
  const int eb = tid & 15;
  const int ejj = tid >> 4;            // 0..7 (wave 0: j 0-3, wave 1: j 4-7)
  const int b_glob = bg * 16 + eb;
  const int j_glob = cg * 8 + ejj;
  const int set = ejj >> 2, jn = ejj & 3;
  float c = 0.0f;

  unsigned long long* hb = (unsigned long long*)hist;
  const size_t hbase = (size_t)(kh * 64 + lkg) * 64 + bg * 16 + lr;

  // xg per-q pointers (bf16 units)
  const bf16* xq0 = xg + (size_t)(0 * 128 + cg) * 16384 * 8 + ejj;
  const bf16* xq1 = xg + (size_t)(1 * 128 + cg) * 16384 * 8 + ejj;
  const bf16* xq2 = xg + (size_t)(2 * 128 + cg) * 16384 * 8 + ejj;
  const bf16* xq3 = xg + (size_t)(3 * 128 + cg) * 16384 * 8 + ejj;
  unsigned short xv0, xv1, xv2, xv3;
  {
    const size_t xidx = (size_t)b_glob * xbs;   // t = 0
    xv0 = *(const unsigned short*)&xq0[xidx * 8];
    xv1 = *(const unsigned short*)&xq1[xidx * 8];
    xv2 = *(const unsigned short*)&xq2[xidx * 8];
    xv3 = *(const unsigned short*)&xq3[xidx * 8];
  }

  const unsigned long long* fv = (const unsigned long long*)flags + (size_t)bg * 128;

#pragma unroll 1
  for (int t = 0; t < TSTEPS; ++t) {
    if (t > 0) {
      const unsigned tt = (unsigned)t;
      for (;;) {
        unsigned long long fa = load_u64_agent(&fv[l]);
        unsigned long long fb = load_u64_agent(&fv[64 + l]);
        int ok = ((unsigned)fa >= tt) && ((unsigned)(fa >> 32) >= tt) &&
                 ((unsigned)fb >= tt) && ((unsigned)(fb >> 32) >= tt);
        if (__all(ok)) break;
        __builtin_amdgcn_s_sleep(1);
      }
    }
    __builtin_amdgcn_sched_barrier(0);
    asm volatile("" ::: "memory");     // no hoisting of h loads above the poll

    const unsigned long long* hin = hb + (size_t)(TSTEPS - t) * HSLOT;
    ffrag a0 = ffrag{0.f, 0.f, 0.f, 0.f};
    ffrag a1 = ffrag{0.f, 0.f, 0.f, 0.f};
#pragma unroll
    for (int ks = 0; ks < 16; ++ks) {
      union { unsigned long long u[2]; bfrag f; } au;
      au.u[0] = hin[hbase + ks * 256];          // cached (write-once slots)
      au.u[1] = hin[8192 + hbase + ks * 256];
      a0 = mfma16(au.f, breg0[ks], a0);
      a1 = mfma16(au.f, breg1[ks], a1);
    }
#pragma unroll
    for (int r = 0; r < 4; ++r) {
      gxp[kh][lkg * 4 + r][lr]      = a0[r];
      gxp[kh][lkg * 4 + r][16 + lr] = a1[r];
    }
    __syncthreads();   // gxp ready (both K-halves)

    const float gi = gxp[0][eb][set * 16 + jn]      + gxp[1][eb][set * 16 + jn]      + bs2f(xv0);
    const float gf = gxp[0][eb][set * 16 + 4 + jn]  + gxp[1][eb][set * 16 + 4 + jn]  + bs2f(xv1);
    const float gg = gxp[0][eb][set * 16 + 8 + jn]  + gxp[1][eb][set * 16 + 8 + jn]  + bs2f(xv2);
    const float go = gxp[0][eb][set * 16 + 12 + jn] + gxp[1][eb][set * 16 + 12 + jn] + bs2f(xv3);
    const float iv = sigm(gi), fvv = sigm(gf), gv = tanhfast(gg), ov = sigm(go);
    c = fvv * c + iv * gv;
    const float h = ov * tanhfast(c);
    const unsigned short hbits = (unsigned short)f2bs(h);

    // h(t+1) -> slot 255-t; a wave's 64 x 2B stores form exactly one 128B line
    unsigned long long* hout = hb + (size_t)(255 - t) * HSLOT;
    unsigned short* hp = (unsigned short*)(hout + (size_t)set * 8192 + cg * 64 + b_glob) + jn;
    store_u16_agent(hp, hbits);

    if (t < TSTEPS - 1) {
      __builtin_amdgcn_s_waitcnt(0);   // h line acked at coherence point
      if (l == 0) store_u32_agent(&flags[bg * 256 + cg * 2 + w], (unsigned)(t + 1));
      // prefetch next step's xg (cached; overlaps flag propagation)
      const size_t xidx = (size_t)b_glob * xbs + (size_t)(t + 1) * xts;
      xv0 = *(const unsigned short*)&xq0[xidx * 8];
      xv1 = *(const unsigned short*)&xq1[xidx * 8];
      xv2 = *(const unsigned short*)&xq2[xidx * 8];
      xv3 = *(const unsigned short*)&xq3[xidx * 8];
    } else {
      out_h[(size_t)b_glob * HDIM + j_glob] = h;
      out_c[(size_t)b_glob * HDIM + j_glob] = c;
      if (out_last) out_last[(size_t)b_glob * HDIM + j_glob] = h;
    }
  }
}

// ---------------- logits = h_T @ W_proj^T + b_proj ----------------
// hfin = final h slot (slot 0 of the descending history).
__launch_bounds__(256, 2)
__global__ void logits_kernel(const bf16* __restrict__ hfin,
                              const float* __restrict__ Wp,   // (32000,1024) f32
                              const float* __restrict__ bp,
                              float* __restrict__ out) {      // (64,32000)
  const int tid = threadIdx.x;
  const int w = tid >> 6, l = tid & 63;
  const int lr = l & 15, lkg = l >> 4, lk = lkg * 8;
  const int col = blockIdx.x * 64 + w * 16 + lr;
  const float* wrow = &Wp[(size_t)col * HDIM];
  const unsigned long long* hb = (const unsigned long long*)hfin;
  ffrag acc[4];
#pragma unroll
  for (int i = 0; i < 4; ++i) acc[i] = ffrag{0.f, 0.f, 0.f, 0.f};
#pragma unroll 2
  for (int ks = 0; ks < 32; ++ks) {
    const int k = ks * 32 + lk;
    float4 wa = *reinterpret_cast<const float4*>(&wrow[k]);
    float4 wb = *reinterpret_cast<const float4*>(&wrow[k + 4]);
    bfrag bv;
    bv[0] = f2bs(wa.x); bv[1] = f2bs(wa.y); bv[2] = f2bs(wa.z); bv[3] = f2bs(wa.w);
    bv[4] = f2bs(wb.x); bv[5] = f2bs(wb.y); bv[6] = f2bs(wb.z); bv[7] = f2bs(wb.w);
    const size_t kg = (size_t)(ks * 4 + lkg);
#pragma unroll
    for (int i = 0; i < 4; ++i) {
      union { unsigned long long u[2]; bfrag f; } av;
      av.u[0] = hb[kg * 64 + i * 16 + lr];
      av.u[1] = hb[8192 + kg * 64 + i * 16 + lr];
      acc[i] = mfma16(av.f, bv, acc[i]);
    }
  }
  const float bias = bp[col];
#pragma unroll
  for (int i = 0; i < 4; ++i) {
#pragma unroll
    for (int r = 0; r < 4; ++r) {
      const int b = i * 16 + (l >> 4) * 4 + r;
      out[(size_t)b * VOCAB + col] = acc[i][r] + bias;
    }
  }
}

extern "C" void kernel_launch(void* const* d_in, const int* in_sizes, int n_in,
                              void* d_out, int out_size, void* d_ws, size_t ws_size,
                              hipStream_t stream) {
  const int*   ids   = (const int*)d_in[0];
  const float* table = (const float*)d_in[1];
  const float* Wih   = (const float*)d_in[2];
  const float* Whh   = (const float*)d_in[3];
  const float* bih   = (const float*)d_in[4];
  const float* bhh   = (const float*)d_in[5];
  const float* Wp    = (const float*)d_in[6];
  const float* bp    = (const float*)d_in[7];
  float* out = (float*)d_out;

  char* ws = (char*)d_ws;
  const size_t HISTB = 257ull * 131072ull;                    // 33,685,504
  const size_t OFF_XG  = 0;                                   // 134,217,728
  const size_t OFF_HA  = OFF_XG + (size_t)512 * 16384 * 8 * 2;// histA; slots 0-255 alias xb
  const size_t OFF_HB  = OFF_HA + HISTB;
  const size_t OFF_WIH = OFF_HB + HISTB;
  const size_t OFF_WHH = OFF_WIH + (size_t)2 * GDIM * HDIM * 2;
  const size_t OFF_SYNC= OFF_WHH + (size_t)2 * GDIM * HDIM * 2;

  bf16* xg    = (bf16*)(ws + OFF_XG);
  bf16* xb    = (bf16*)(ws + OFF_HA);   // embeddings (32 MB) = histA slots 0-255
  bf16* histA = (bf16*)(ws + OFF_HA);
  bf16* histB = (bf16*)(ws + OFF_HB);
  bf16* wihb  = (bf16*)(ws + OFF_WIH);
  bf16* whhb  = (bf16*)(ws + OFF_WHH);
  unsigned* sync = (unsigned*)(ws + OFF_SYNC);

  (void)hipMemsetAsync(sync, 0, 16384, stream);
  (void)hipMemsetAsync(ws + OFF_HA + 33554432ull, 0, 131072, stream);  // histA slot 256 (h0=0)
  (void)hipMemsetAsync(ws + OFF_HB + 33554432ull, 0, 131072, stream);  // histB slot 256

  const int nconv4 = 2 * GDIM * HDIM / 4;
  convert_bf16_kernel<<<nconv4 / 256, 256, 0, stream>>>(Wih, wihb, nconv4);
  convert_bf16_kernel<<<nconv4 / 256, 256, 0, stream>>>(Whh, whhb, nconv4);
  const int nemb4 = BATCH * TSTEPS * HDIM / 4;
  embed_kernel<<<nemb4 / 256, 256, 0, stream>>>(ids, table, xb, nemb4);

  float* out_last   = out;              // (64,1024)
  float* out_logits = out + 65536;      // (64,32000)
  float* out_hn     = out + 2113536;    // (2,64,1024)
  float* out_cn     = out + 2244608;    // (2,64,1024)

  // ---- layer 1 ----
  gemm_xg_kernel<0><<<dim3(GDIM / BNX, (BATCH * TSTEPS) / BMX), 256, 0, stream>>>(
      xb, wihb, bih, bhh, xg);
  lstm_seq_kernel<<<512, 128, 0, stream>>>(
      xg, whhb, histA, out_hn, out_cn, nullptr, sync, 256, 1);

  // ---- layer 2 ----
  gemm_xg_kernel<1><<<dim3(GDIM / BNX, (BATCH * TSTEPS) / BMX), 256, 0, stream>>>(
      histA, wihb + (size_t)GDIM * HDIM, bih + GDIM, bhh + GDIM, xg);
  lstm_seq_kernel<<<512, 128, 0, stream>>>(
      xg, whhb + (size_t)GDIM * HDIM, histB,
      out_hn + (size_t)BATCH * HDIM, out_cn + (size_t)BATCH * HDIM,
      out_last, sync + 1024, 1, 64);

  logits_kernel<<<VOCAB / 64, 256, 0, stream>>>(histB, Wp, bp, out_logits);
}